// Round 4
// baseline (4679.898 us; speedup 1.0000x reference)
//
#include <hip/hip_runtime.h>

// Seq2SeqLSTMForecaster on MI355X — round 14.
// R13 FAILED post-timing determinism (first launch != stable later launches)
// after the only change was __launch_bounds__(512,1). Cannot attribute the
// exact mechanism without disasm -> revert ALL launch bounds to R12's
// passing (512,2) config.
// This round's single change: kill kD's scratch storm WITHOUT touching
// launch bounds. R12 kD: VGPR=112, FETCH 4.47GB/dispatch @950us = the
// w0[4][32] weight array spilled to scratch and reloaded from HBM all 96
// steps. Fix: drop the register array; kPrep repacks dec_Whh0 into the
// gate-contiguous [k][hid][4] layout (same as packD1), and kD phase-1
// streams one coalesced float4 per k from global (L2-resident, 256KB).
// Same FMA order -> bit-identical math to R12.
//  kA2/kB3/kXm: byte-identical to round 12.

#define B_    1024
#define T_    672
#define H_    128
#define G_    512      // 4*H
#define TGT_  96
#define NBLK_ 256

typedef __attribute__((ext_vector_type(8))) short  short8;
typedef __attribute__((ext_vector_type(4))) float  floatx4;

__device__ __forceinline__ float sigm(float x)   { return 1.f / (1.f + __expf(-x)); }
__device__ __forceinline__ float tanh_f(float x) { return 1.f - 2.f / (1.f + __expf(2.f * x)); }

// fp32 -> bf16 hi (RNE-ish) + bf16 lo of the residual.
__device__ __forceinline__ void bsplit(float a, unsigned short& h, unsigned short& l) {
    const unsigned int u  = __float_as_uint(a);
    const unsigned int hi = (u + 0x8000u) >> 16;
    const float fh = __uint_as_float(hi << 16);
    h = (unsigned short)hi;
    l = (unsigned short)(__float_as_uint(a - fh) >> 16);
}

// ---------------------------------------------------------------- prep ------
struct PrepArgs {
    const float* dwhh0; float* pk0;                   // kD L0 weights -> [k][hid][4]
    const float* d1x; const float* d1h; float* pack;  // kD dec L1 pack
    const float* bsrc[3];        // eWih1, eWhh0, eWhh1  (all [512][128] = [n][k])
    unsigned short* bh[3];
    unsigned short* bl[3];
};

__global__ void kPrep(PrepArgs a) {
    const int m = blockIdx.x;
    if (m == 0) {
        // pk0[(k*128 + j4)*4 + g] = dWhh0[j4+128g][k]  (gate-contiguous float4)
        for (int i = threadIdx.x; i < H_ * H_; i += blockDim.x) {
            const int k = i >> 7, j4 = i & 127;
            float* p = a.pk0 + ((size_t)k * H_ + j4) * 4;
#pragma unroll
            for (int g = 0; g < 4; g++)
                p[g] = a.dwhh0[(j4 + 128 * g) * H_ + k];
        }
    } else if (m == 1) {
        // pack[(k*128 + j4)*8 + g]   = dWih1[j4+128g][k]  (g=0..3)
        // pack[(k*128 + j4)*8 + 4+g] = dWhh1[j4+128g][k]
        for (int i = threadIdx.x; i < H_ * H_; i += blockDim.x) {
            const int k = i >> 7, j4 = i & 127;
            float* p = a.pack + ((size_t)k * H_ + j4) * 8;
#pragma unroll
            for (int g = 0; g < 4; g++) {
                p[g]     = a.d1x[(j4 + 128 * g) * H_ + k];
                p[4 + g] = a.d1h[(j4 + 128 * g) * H_ + k];
            }
        }
    } else {
        const int s = m - 2;
        const float* src = a.bsrc[s];
        unsigned short* dh = a.bh[s];
        unsigned short* dl = a.bl[s];
        for (int i = threadIdx.x; i < G_ * H_; i += blockDim.x) {
            unsigned short h, l;
            bsplit(src[i], h, l);
            dh[i] = h; dl[i] = l;
        }
    }
}

// ------------------- enc L0: MFMA recurrent, 16 batches/block ---------------
__global__ __launch_bounds__(512, 2) void kA2(
    const float* __restrict__ feat,          // [B, T]
    const unsigned short* __restrict__ WHh,  // eWhh0 bf16-hi [512][128]
    const unsigned short* __restrict__ WHl,  // lo
    const float* __restrict__ wih0,          // [512]
    const float* __restrict__ bias,          // [512]
    unsigned short* __restrict__ Ah,         // [CL][1024][128] bf16-hi of h
    unsigned short* __restrict__ Al,         // lo
    float* __restrict__ hS, float* __restrict__ cS,
    int t0, int CL)
{
    __shared__ __align__(16) unsigned short hh[2][16][136];
    __shared__ __align__(16) unsigned short hl[2][16][136];
    __shared__ __align__(16) float fsh[672];   // [dt][16]

    const int tid  = threadIdx.x;
    const int lane = tid & 63;
    const int w    = tid >> 6;       // wave 0..7
    const int c15  = lane & 15;
    const int q    = lane >> 4;      // 0..3
    const int BG   = blockIdx.x * 16;

    // B-fragments: wave w's gates n = 16w + 128g + c15; k = 32kt + 8q + j.
    short8 wh[4][4], wl[4][4];
#pragma unroll
    for (int g = 0; g < 4; g++)
#pragma unroll
        for (int kt = 0; kt < 4; kt++) {
            const size_t off = (size_t)(16 * w + 128 * g + c15) * H_ + 32 * kt + 8 * q;
            wh[g][kt] = *(const short8*)(WHh + off);
            wl[g][kt] = *(const short8*)(WHl + off);
        }

    float bz[4], wx[4];
#pragma unroll
    for (int g = 0; g < 4; g++) {
        bz[g] = bias[16 * w + 128 * g + c15];
        wx[g] = wih0[16 * w + 128 * g + c15];
    }

    for (int i = tid; i < CL * 16; i += 512)
        fsh[i] = feat[(BG + (i & 15)) * T_ + t0 + (i >> 4)];

    float cc[4], hv[4];
#pragma unroll
    for (int r = 0; r < 4; r++) { cc[r] = 0.f; hv[r] = 0.f; }
    if (t0 != 0) {
#pragma unroll
        for (int r = 0; r < 4; r++) {
            const size_t si = (size_t)(BG + 4 * q + r) * H_ + 16 * w + c15;
            cc[r] = cS[si]; hv[r] = hS[si];
        }
    }
#pragma unroll
    for (int r = 0; r < 4; r++) {
        unsigned short hi, lo; bsplit(hv[r], hi, lo);
        hh[0][4 * q + r][16 * w + c15] = hi;
        hl[0][4 * q + r][16 * w + c15] = lo;
    }
    __syncthreads();

    int pb = 0;
    unsigned int hp[4];    // packed h(dt-1): hi | lo<<16, for deferred store

    for (int dt = 0; dt < CL; dt++) {
        if (dt > 0) {
#pragma unroll
            for (int r = 0; r < 4; r++) {
                const size_t ai = ((size_t)(dt - 1) * B_ + BG + 4 * q + r) * H_ + 16 * w + c15;
                Ah[ai] = (unsigned short)(hp[r] & 0xffffu);
                Al[ai] = (unsigned short)(hp[r] >> 16);
            }
        }

        floatx4 acc[4];
#pragma unroll
        for (int g = 0; g < 4; g++) acc[g] = (floatx4){0.f, 0.f, 0.f, 0.f};

#pragma unroll
        for (int kt = 0; kt < 4; kt++) {
            const short8 ahv = *(const short8*)&hh[pb][c15][32 * kt + 8 * q];
            const short8 alv = *(const short8*)&hl[pb][c15][32 * kt + 8 * q];
#pragma unroll
            for (int g = 0; g < 4; g++) {
                acc[g] = __builtin_amdgcn_mfma_f32_16x16x32_bf16(ahv, wh[g][kt], acc[g], 0, 0, 0);
                acc[g] = __builtin_amdgcn_mfma_f32_16x16x32_bf16(ahv, wl[g][kt], acc[g], 0, 0, 0);
                acc[g] = __builtin_amdgcn_mfma_f32_16x16x32_bf16(alv, wh[g][kt], acc[g], 0, 0, 0);
            }
        }

        const int nb = pb ^ 1;
#pragma unroll
        for (int r = 0; r < 4; r++) {
            const float x = fsh[dt * 16 + 4 * q + r];
            const float zi = acc[0][r] + __fmaf_rn(wx[0], x, bz[0]);
            const float zf = acc[1][r] + __fmaf_rn(wx[1], x, bz[1]);
            const float zg = acc[2][r] + __fmaf_rn(wx[2], x, bz[2]);
            const float zo = acc[3][r] + __fmaf_rn(wx[3], x, bz[3]);
            cc[r] = sigm(zf) * cc[r] + sigm(zi) * tanh_f(zg);
            const float h = sigm(zo) * tanh_f(cc[r]);
            hv[r] = h;
            unsigned short hi, lo; bsplit(h, hi, lo);
            hp[r] = (unsigned int)hi | ((unsigned int)lo << 16);
            hh[nb][4 * q + r][16 * w + c15] = hi;
            hl[nb][4 * q + r][16 * w + c15] = lo;
        }
        __syncthreads();
        pb = nb;
    }

#pragma unroll
    for (int r = 0; r < 4; r++) {
        const size_t ai = ((size_t)(CL - 1) * B_ + BG + 4 * q + r) * H_ + 16 * w + c15;
        Ah[ai] = (unsigned short)(hp[r] & 0xffffu);
        Al[ai] = (unsigned short)(hp[r] >> 16);
        const size_t si = (size_t)(BG + 4 * q + r) * H_ + 16 * w + c15;
        hS[si] = hv[r]; cS[si] = cc[r];
    }
}

// ----------------------- X1 GEMM via MFMA bf16 split-2 ----------------------
__global__ __launch_bounds__(256, 2) void kXm(
    const unsigned short* __restrict__ Ah,  // [CL][1024][128]
    const unsigned short* __restrict__ Al,
    const unsigned short* __restrict__ Wh,  // [512][128]
    const unsigned short* __restrict__ Wl,
    const float* __restrict__ bias,         // [512]
    float* __restrict__ X1)                 // [CL][1024][512]
{
    __shared__ __align__(16) unsigned short Bh[128 * 128];
    __shared__ __align__(16) unsigned short Bl[128 * 128];

    const int tid = threadIdx.x;
    const int n0  = blockIdx.y * 128;

    for (int c = tid; c < 2048; c += 256) {
        const int n  = c >> 4;
        const int kb = (c & 15) << 4;
        const int sb = n * 256 + (kb ^ ((n & 7) << 4));
        *(float4*)((char*)Bh + sb) =
            *(const float4*)((const char*)Wh + (size_t)(n0 + n) * 256 + kb);
        *(float4*)((char*)Bl + sb) =
            *(const float4*)((const char*)Wl + (size_t)(n0 + n) * 256 + kb);
    }
    __syncthreads();

    const int lane = tid & 63;
    const int w    = tid >> 6;
    const int l15  = lane & 15;
    const int lq   = lane >> 4;
    const int dt   = blockIdx.z;
    const int m0   = blockIdx.x * 128 + w * 32;

    const size_t arow = ((size_t)dt * B_ + m0 + l15) * H_;
    const unsigned short* a0h = Ah + arow;
    const unsigned short* a0l = Al + arow;

    floatx4 acc[2][8];
#pragma unroll
    for (int i = 0; i < 2; i++)
#pragma unroll
        for (int j = 0; j < 8; j++)
            acc[i][j] = (floatx4){0.f, 0.f, 0.f, 0.f};

#pragma unroll
    for (int ks = 0; ks < 4; ks++) {
        const int kk = ks * 32 + 8 * lq;
        const short8 ah0 = *(const short8*)(a0h + kk);
        const short8 al0 = *(const short8*)(a0l + kk);
        const short8 ah1 = *(const short8*)(a0h + 16 * H_ + kk);
        const short8 al1 = *(const short8*)(a0l + 16 * H_ + kk);
        const int kbb = kk * 2;
#pragma unroll
        for (int nt = 0; nt < 8; nt++) {
            const int row = nt * 16 + l15;
            const int sb  = row * 256 + (kbb ^ ((row & 7) << 4));
            const short8 bh = *(const short8*)((const char*)Bh + sb);
            const short8 bl = *(const short8*)((const char*)Bl + sb);
            acc[0][nt] = __builtin_amdgcn_mfma_f32_16x16x32_bf16(ah0, bh, acc[0][nt], 0, 0, 0);
            acc[1][nt] = __builtin_amdgcn_mfma_f32_16x16x32_bf16(ah1, bh, acc[1][nt], 0, 0, 0);
            acc[0][nt] = __builtin_amdgcn_mfma_f32_16x16x32_bf16(ah0, bl, acc[0][nt], 0, 0, 0);
            acc[1][nt] = __builtin_amdgcn_mfma_f32_16x16x32_bf16(ah1, bl, acc[1][nt], 0, 0, 0);
            acc[0][nt] = __builtin_amdgcn_mfma_f32_16x16x32_bf16(al0, bh, acc[0][nt], 0, 0, 0);
            acc[1][nt] = __builtin_amdgcn_mfma_f32_16x16x32_bf16(al1, bh, acc[1][nt], 0, 0, 0);
        }
    }

#pragma unroll
    for (int nt = 0; nt < 8; nt++) {
        const float bv = bias[n0 + nt * 16 + l15];
#pragma unroll
        for (int mt = 0; mt < 2; mt++) {
            const size_t orow =
                ((size_t)dt * B_ + m0 + mt * 16 + lq * 4) * G_ + n0 + nt * 16 + l15;
#pragma unroll
            for (int r = 0; r < 4; r++)
                X1[orow + (size_t)r * G_] = acc[mt][nt][r] + bv;
        }
    }
}

// ------------------- enc L1: MFMA recurrent, 16 batches/block ---------------
__global__ __launch_bounds__(512, 2) void kB3(
    const float* __restrict__ X1,            // [CL][B][512]
    const unsigned short* __restrict__ WHh,  // eWhh1 bf16-hi [512][128]
    const unsigned short* __restrict__ WHl,
    float* __restrict__ hS, float* __restrict__ cS,
    int t0, int CL)
{
    __shared__ __align__(16) unsigned short hh[2][16][136];
    __shared__ __align__(16) unsigned short hl[2][16][136];

    const int tid  = threadIdx.x;
    const int lane = tid & 63;
    const int w    = tid >> 6;
    const int c15  = lane & 15;
    const int q    = lane >> 4;
    const int BG   = blockIdx.x * 16;

    short8 wh[4][4], wl[4][4];
#pragma unroll
    for (int g = 0; g < 4; g++)
#pragma unroll
        for (int kt = 0; kt < 4; kt++) {
            const size_t off = (size_t)(16 * w + 128 * g + c15) * H_ + 32 * kt + 8 * q;
            wh[g][kt] = *(const short8*)(WHh + off);
            wl[g][kt] = *(const short8*)(WHl + off);
        }

    float cc[4], hv[4];
#pragma unroll
    for (int r = 0; r < 4; r++) { cc[r] = 0.f; hv[r] = 0.f; }
    if (t0 != 0) {
#pragma unroll
        for (int r = 0; r < 4; r++) {
            const size_t si = (size_t)(BG + 4 * q + r) * H_ + 16 * w + c15;
            cc[r] = cS[si]; hv[r] = hS[si];
        }
    }
#pragma unroll
    for (int r = 0; r < 4; r++) {
        unsigned short hi, lo; bsplit(hv[r], hi, lo);
        hh[0][4 * q + r][16 * w + c15] = hi;
        hl[0][4 * q + r][16 * w + c15] = lo;
    }
    __syncthreads();

    int pb = 0;

    for (int dt = 0; dt < CL; dt++) {
        float x1v[4][4];
#pragma unroll
        for (int g = 0; g < 4; g++)
#pragma unroll
            for (int r = 0; r < 4; r++)
                x1v[g][r] = X1[((size_t)dt * B_ + BG + 4 * q + r) * G_ + 16 * w + 128 * g + c15];

        floatx4 acc[4];
#pragma unroll
        for (int g = 0; g < 4; g++) acc[g] = (floatx4){0.f, 0.f, 0.f, 0.f};

#pragma unroll
        for (int kt = 0; kt < 4; kt++) {
            const short8 ahv = *(const short8*)&hh[pb][c15][32 * kt + 8 * q];
            const short8 alv = *(const short8*)&hl[pb][c15][32 * kt + 8 * q];
#pragma unroll
            for (int g = 0; g < 4; g++) {
                acc[g] = __builtin_amdgcn_mfma_f32_16x16x32_bf16(ahv, wh[g][kt], acc[g], 0, 0, 0);
                acc[g] = __builtin_amdgcn_mfma_f32_16x16x32_bf16(ahv, wl[g][kt], acc[g], 0, 0, 0);
                acc[g] = __builtin_amdgcn_mfma_f32_16x16x32_bf16(alv, wh[g][kt], acc[g], 0, 0, 0);
            }
        }

        const int nb = pb ^ 1;
#pragma unroll
        for (int r = 0; r < 4; r++) {
            const float zi = acc[0][r] + x1v[0][r];
            const float zf = acc[1][r] + x1v[1][r];
            const float zg = acc[2][r] + x1v[2][r];
            const float zo = acc[3][r] + x1v[3][r];
            cc[r] = sigm(zf) * cc[r] + sigm(zi) * tanh_f(zg);
            const float h = sigm(zo) * tanh_f(cc[r]);
            hv[r] = h;
            unsigned short hi, lo; bsplit(h, hi, lo);
            hh[nb][4 * q + r][16 * w + c15] = hi;
            hl[nb][4 * q + r][16 * w + c15] = lo;
        }
        __syncthreads();
        pb = nb;
    }

#pragma unroll
    for (int r = 0; r < 4; r++) {
        const size_t si = (size_t)(BG + 4 * q + r) * H_ + 16 * w + c15;
        hS[si] = hv[r]; cS[si] = cc[r];
    }
}

// ------------------------------------------- decoder (quad-gate both dots) --
__global__ __launch_bounds__(512, 2) void kD(
    const float* __restrict__ h1S, const float* __restrict__ c1S,
    const float* __restrict__ h2S, const float* __restrict__ c2S,
    const float* __restrict__ whh0P,  // [128][128][4] dec_Whh0 gate-packed (L2 stream)
    const float* __restrict__ wih0,   // [512]
    const float* __restrict__ b0,
    const float* __restrict__ packD1, // [128][128][8]
    const float* __restrict__ b1,
    const float* __restrict__ wo1,    // [128][128] W_out1 [hid][k] -> LDS rows
    const float* __restrict__ bo1,
    const float* __restrict__ wo2,
    const float* __restrict__ bo2,
    float* __restrict__ out)          // [B,TGT]
{
    __shared__ __align__(16) float h1_sh[H_ * 4];
    __shared__ __align__(16) float h2_sh[H_ * 4];
    __shared__ __align__(16) float h2t[4][H_];       // [bb][hid]
    __shared__ __align__(16) float zp[4 * 2048];
    __shared__ __align__(16) float wo1s[H_ * 132];   // rows [hid][k], pad 132
    __shared__ float rp[8];

    const int tid = threadIdx.x;
    const int hid = tid & 127;        // gate group / act hid
    const int bb  = tid >> 7;         // k-quarter / act batch
    const int B0  = blockIdx.x * 4;

    const float b0i = b0[hid],        b0f = b0[hid + 128];
    const float b0g = b0[hid + 256],  b0o = b0[hid + 384];
    const float wxi = wih0[hid],      wxf = wih0[hid + 128];
    const float wxg = wih0[hid + 256], wxo = wih0[hid + 384];
    const float b1i = b1[hid],        b1f = b1[hid + 128];
    const float b1g = b1[hid + 256],  b1o = b1[hid + 384];

    for (int t = tid; t < H_ * 32; t += 512) {
        const int r = t >> 5, q = t & 31;
        *(float4*)&wo1s[r * 132 + q * 4] = *(const float4*)&wo1[r * H_ + q * 4];
    }

    const float wo2v = wo2[hid];
    const float bo1j = bo1[hid];
    const float bo2v = bo2[0];

    float c1 = c1S[(B0 + bb) * H_ + hid];
    float c2 = c2S[(B0 + bb) * H_ + hid];
    h1_sh[hid * 4 + bb] = h1S[(B0 + bb) * H_ + hid];
    {
        const float h2v = h2S[(B0 + bb) * H_ + hid];
        h2_sh[hid * 4 + bb] = h2v;
        h2t[bb][hid] = h2v;
    }
    if (tid < 8) rp[tid] = -0.5f * bo2v;   // so pred(step 0) = 0
    __syncthreads();

    const float* hb1 = h1_sh + bb * 128;
    const float* hb2 = h2_sh + bb * 128;
    const float* pk  = packD1 + ((size_t)bb * 32 * H_ + hid) * 8;
    const float* pw0 = whh0P + (size_t)bb * 32 * 512 + hid * 4;   // [k][hid][4] slice

    for (int s = 0; s < TGT_; s++) {
        // ===== phase 1: L0 h-dot (L2 weight stream) + head of h2(s-1) =====
        {
            float a[4][4] = {};
#pragma unroll 8
            for (int k = 0; k < 32; k++) {
                const float4 wv = *(const float4*)&pw0[(size_t)k * 512];  // gates i,f,g,o
                const float4 h4 = *(const float4*)&hb1[k * 4];
                a[0][0] = __fmaf_rn(h4.x, wv.x, a[0][0]);
                a[0][1] = __fmaf_rn(h4.y, wv.x, a[0][1]);
                a[0][2] = __fmaf_rn(h4.z, wv.x, a[0][2]);
                a[0][3] = __fmaf_rn(h4.w, wv.x, a[0][3]);
                a[1][0] = __fmaf_rn(h4.x, wv.y, a[1][0]);
                a[1][1] = __fmaf_rn(h4.y, wv.y, a[1][1]);
                a[1][2] = __fmaf_rn(h4.z, wv.y, a[1][2]);
                a[1][3] = __fmaf_rn(h4.w, wv.y, a[1][3]);
                a[2][0] = __fmaf_rn(h4.x, wv.z, a[2][0]);
                a[2][1] = __fmaf_rn(h4.y, wv.z, a[2][1]);
                a[2][2] = __fmaf_rn(h4.z, wv.z, a[2][2]);
                a[2][3] = __fmaf_rn(h4.w, wv.z, a[2][3]);
                a[3][0] = __fmaf_rn(h4.x, wv.w, a[3][0]);
                a[3][1] = __fmaf_rn(h4.y, wv.w, a[3][1]);
                a[3][2] = __fmaf_rn(h4.z, wv.w, a[3][2]);
                a[3][3] = __fmaf_rn(h4.w, wv.w, a[3][3]);
            }
#pragma unroll
            for (int g = 0; g < 4; g++)
#pragma unroll
                for (int b = 0; b < 4; b++)
                    zp[bb * 2048 + b * 512 + hid + 128 * g] = a[g][b];
        }
        {
            float hacc = bo1j;
#pragma unroll
            for (int q = 0; q < 32; q++) {
                const float4 hq = *(const float4*)&h2t[bb][q * 4];          // uniform
                const float4 wq = *(const float4*)&wo1s[hid * 132 + q * 4]; // lane-spread
                hacc = __fmaf_rn(hq.x, wq.x, hacc);
                hacc = __fmaf_rn(hq.y, wq.y, hacc);
                hacc = __fmaf_rn(hq.z, wq.z, hacc);
                hacc = __fmaf_rn(hq.w, wq.w, hacc);
            }
            float p = fmaxf(hacc, 0.f) * wo2v;
            p += __shfl_down(p, 32); p += __shfl_down(p, 16); p += __shfl_down(p, 8);
            p += __shfl_down(p, 4);  p += __shfl_down(p, 2);  p += __shfl_down(p, 1);
            if ((tid & 63) == 0) rp[tid >> 6] = p;
        }
        __syncthreads();

        // ===== phase 2: L0 act (+ x-term via pred), out write =====
        {
            const float pred = rp[2 * bb] + rp[2 * bb + 1] + bo2v;
            if (hid == 0 && s > 0) out[(B0 + bb) * TGT_ + (s - 1)] = pred;
            const int base = bb * 512 + hid;
            float zi = __fmaf_rn(wxi, pred, b0i);
            float zf = __fmaf_rn(wxf, pred, b0f);
            float zg = __fmaf_rn(wxg, pred, b0g);
            float zo = __fmaf_rn(wxo, pred, b0o);
#pragma unroll
            for (int q = 0; q < 4; q++) {
                zi += zp[q * 2048 + base];
                zf += zp[q * 2048 + base + 128];
                zg += zp[q * 2048 + base + 256];
                zo += zp[q * 2048 + base + 384];
            }
            c1 = sigm(zf) * c1 + sigm(zi) * tanh_f(zg);
            h1_sh[hid * 4 + bb] = sigm(zo) * tanh_f(c1);
        }
        __syncthreads();

        // ===== phase 3: L1 dot (L2 stream: 32 contiguous B per thread per k) =====
        {
            float d[4][4] = {};
#pragma unroll 8
            for (int k = 0; k < 32; k++) {
                const float4 wi = *(const float4*)&pk[(size_t)k * 1024];
                const float4 wh = *(const float4*)&pk[(size_t)k * 1024 + 4];
                const float4 p1 = *(const float4*)&hb1[k * 4];
                const float4 p2 = *(const float4*)&hb2[k * 4];
                d[0][0] = __fmaf_rn(p1.x, wi.x, __fmaf_rn(p2.x, wh.x, d[0][0]));
                d[0][1] = __fmaf_rn(p1.y, wi.x, __fmaf_rn(p2.y, wh.x, d[0][1]));
                d[0][2] = __fmaf_rn(p1.z, wi.x, __fmaf_rn(p2.z, wh.x, d[0][2]));
                d[0][3] = __fmaf_rn(p1.w, wi.x, __fmaf_rn(p2.w, wh.x, d[0][3]));
                d[1][0] = __fmaf_rn(p1.x, wi.y, __fmaf_rn(p2.x, wh.y, d[1][0]));
                d[1][1] = __fmaf_rn(p1.y, wi.y, __fmaf_rn(p2.y, wh.y, d[1][1]));
                d[1][2] = __fmaf_rn(p1.z, wi.y, __fmaf_rn(p2.z, wh.y, d[1][2]));
                d[1][3] = __fmaf_rn(p1.w, wi.y, __fmaf_rn(p2.w, wh.y, d[1][3]));
                d[2][0] = __fmaf_rn(p1.x, wi.z, __fmaf_rn(p2.x, wh.z, d[2][0]));
                d[2][1] = __fmaf_rn(p1.y, wi.z, __fmaf_rn(p2.y, wh.z, d[2][1]));
                d[2][2] = __fmaf_rn(p1.z, wi.z, __fmaf_rn(p2.z, wh.z, d[2][2]));
                d[2][3] = __fmaf_rn(p1.w, wi.z, __fmaf_rn(p2.w, wh.z, d[2][3]));
                d[3][0] = __fmaf_rn(p1.x, wi.w, __fmaf_rn(p2.x, wh.w, d[3][0]));
                d[3][1] = __fmaf_rn(p1.y, wi.w, __fmaf_rn(p2.y, wh.w, d[3][1]));
                d[3][2] = __fmaf_rn(p1.z, wi.w, __fmaf_rn(p2.z, wh.w, d[3][2]));
                d[3][3] = __fmaf_rn(p1.w, wi.w, __fmaf_rn(p2.w, wh.w, d[3][3]));
            }
#pragma unroll
            for (int g = 0; g < 4; g++)
#pragma unroll
                for (int b = 0; b < 4; b++)
                    zp[bb * 2048 + b * 512 + hid + 128 * g] = d[g][b];
        }
        __syncthreads();

        // ===== phase 4: L1 act =====
        {
            const int base = bb * 512 + hid;
            float zi = b1i, zf = b1f, zg = b1g, zo = b1o;
#pragma unroll
            for (int q = 0; q < 4; q++) {
                zi += zp[q * 2048 + base];
                zf += zp[q * 2048 + base + 128];
                zg += zp[q * 2048 + base + 256];
                zo += zp[q * 2048 + base + 384];
            }
            c2 = sigm(zf) * c2 + sigm(zi) * tanh_f(zg);
            const float h2v = sigm(zo) * tanh_f(c2);
            h2_sh[hid * 4 + bb] = h2v;
            h2t[bb][hid] = h2v;
        }
        __syncthreads();
    }

    // ===== epilogue: head of final h2 -> out[..][95] =====
    {
        float hacc = bo1j;
#pragma unroll
        for (int q = 0; q < 32; q++) {
            const float4 hq = *(const float4*)&h2t[bb][q * 4];
            const float4 wq = *(const float4*)&wo1s[hid * 132 + q * 4];
            hacc = __fmaf_rn(hq.x, wq.x, hacc);
            hacc = __fmaf_rn(hq.y, wq.y, hacc);
            hacc = __fmaf_rn(hq.z, wq.z, hacc);
            hacc = __fmaf_rn(hq.w, wq.w, hacc);
        }
        float p = fmaxf(hacc, 0.f) * wo2v;
        p += __shfl_down(p, 32); p += __shfl_down(p, 16); p += __shfl_down(p, 8);
        p += __shfl_down(p, 4);  p += __shfl_down(p, 2);  p += __shfl_down(p, 1);
        if ((tid & 63) == 0) rp[tid >> 6] = p;
    }
    __syncthreads();
    if (tid < 4)
        out[(B0 + tid) * TGT_ + (TGT_ - 1)] = rp[2 * tid] + rp[2 * tid + 1] + bo2v;
}

// ---------------------------------------------------------------- launch ----
extern "C" void kernel_launch(void* const* d_in, const int* in_sizes, int n_in,
                              void* d_out, int out_size, void* d_ws, size_t ws_size,
                              hipStream_t stream) {
    const float* feat  = (const float*)d_in[0];
    const float* eWih0 = (const float*)d_in[1];
    const float* eWhh0 = (const float*)d_in[2];
    const float* eB0   = (const float*)d_in[3];
    const float* eWih1 = (const float*)d_in[4];
    const float* eWhh1 = (const float*)d_in[5];
    const float* eB1   = (const float*)d_in[6];
    const float* dWih0 = (const float*)d_in[7];
    const float* dWhh0 = (const float*)d_in[8];
    const float* dB0   = (const float*)d_in[9];
    const float* dWih1 = (const float*)d_in[10];
    const float* dWhh1 = (const float*)d_in[11];
    const float* dB1   = (const float*)d_in[12];
    const float* Wo1   = (const float*)d_in[13];
    const float* bo1   = (const float*)d_in[14];
    const float* Wo2   = (const float*)d_in[15];
    const float* bo2   = (const float*)d_in[16];

    const size_t SZ_BH = (size_t)B_ * H_;     // 131072
    const size_t SZ_W  = (size_t)G_ * H_;     // 65536
    // fixed: h/c states (4*BH) + pk0 (W/2... stored as SZ_W/... see layout) +
    // pack (2W) + 3 bf16 split pairs (3W) -> keep R12's 6W envelope (pk0 = W/2
    // floats fits the old wtD0 slot of W floats).
    const size_t fixed_f = 4 * SZ_BH + 6 * SZ_W + 64;

    // CL <= 42 so X1 + A-halves stay L3-resident
    static const int cands[] = {42, 32, 28, 24, 21, 16, 14, 12, 8, 7, 6, 4, 3, 2, 1};
    int CL = 1;
    for (int ci = 0; ci < 15; ci++) {
        const size_t need = (fixed_f + (size_t)cands[ci] * B_ * (H_ + G_)) * 4;
        if (need <= ws_size) { CL = cands[ci]; break; }
    }
    const int NC = T_ / CL;

    float* ws = (float*)d_ws;
    unsigned short* Ah = (unsigned short*)ws;            // [CL][1024][128] bf16-hi
    unsigned short* Al = Ah + (size_t)CL * B_ * H_;      // [CL][1024][128] bf16-lo
    float* X1    = ws + (size_t)CL * B_ * H_;            // [CL][1024][512]
    float* h1S   = X1 + (size_t)CL * B_ * G_;
    float* c1S   = h1S + SZ_BH;
    float* h2S   = c1S + SZ_BH;
    float* c2S   = h2S + SZ_BH;
    float* pk0   = c2S + SZ_BH;                          // [128][128][4] (in old wtD0 slot, SZ_W floats)
    float* wtD1p = pk0 + SZ_W;                           // [128][128][8] = 2*SZ_W
    unsigned short* Wh  = (unsigned short*)(wtD1p + 2 * SZ_W);  // eWih1 split
    unsigned short* Wl  = Wh + SZ_W;
    unsigned short* H0h = Wl + SZ_W;                            // eWhh0 split
    unsigned short* H0l = H0h + SZ_W;
    unsigned short* H1h = H0l + SZ_W;                           // eWhh1 split
    unsigned short* H1l = H1h + SZ_W;

    PrepArgs pa;
    pa.dwhh0 = dWhh0; pa.pk0 = pk0;
    pa.d1x = dWih1; pa.d1h = dWhh1; pa.pack = wtD1p;
    pa.bsrc[0] = eWih1; pa.bh[0] = Wh;  pa.bl[0] = Wl;
    pa.bsrc[1] = eWhh0; pa.bh[1] = H0h; pa.bl[1] = H0l;
    pa.bsrc[2] = eWhh1; pa.bh[2] = H1h; pa.bl[2] = H1l;
    kPrep<<<5, 256, 0, stream>>>(pa);

    for (int c = 0; c < NC; c++) {
        const int t0 = c * CL;
        kA2<<<64, 512, 0, stream>>>(feat, H0h, H0l, eWih0, eB0, Ah, Al, h1S, c1S, t0, CL);
        kXm<<<dim3(8, 4, CL), 256, 0, stream>>>(Ah, Al, Wh, Wl, eB1, X1);
        kB3<<<64, 512, 0, stream>>>(X1, H1h, H1l, h2S, c2S, t0, CL);
    }
    kD<<<NBLK_, 512, 0, stream>>>(h1S, c1S, h2S, c2S,
                                  pk0, dWih0, dB0,
                                  wtD1p, dB1,
                                  Wo1, bo1, Wo2, bo2,
                                  (float*)d_out);
}

// Round 5
// 3287.378 us; speedup vs baseline: 1.4236x; 1.4236x over previous
//
#include <hip/hip_runtime.h>

// Seq2SeqLSTMForecaster on MI355X — round 15.
// R14 post-mortem: FETCH_SIZE is KB — kD fetches 4.45 MB (not GB); the
// scratch-storm theory was a unit misread. Real ledger: kD ~1.0ms and
// kA2+kB3 ~2.9ms, all latency/issue-bound serial recurrences; kA2/kB3 run
// on only 64 of 256 CUs (75% of the chip dark for 63% of runtime).
// This round, ONE structural change (zero math change): chunk-pipeline
// fusion. kF(c) = blocks 0..63 run L0(chunk c), blocks 64..127 run
// L1(chunk c-1) concurrently on disjoint CUs/state. Stream order provides
// all deps: kXm(c-1) < F(c) < kXm(c). 17 fused launches replace 32;
// recurrent wall = sum(max) instead of sum(sum).
//  Device bodies of L0/L1: verbatim R14 kA2/kB3. kXm/kD: byte-identical.

#define B_    1024
#define T_    672
#define H_    128
#define G_    512      // 4*H
#define TGT_  96
#define NBLK_ 256

typedef __attribute__((ext_vector_type(8))) short  short8;
typedef __attribute__((ext_vector_type(4))) float  floatx4;

__device__ __forceinline__ float sigm(float x)   { return 1.f / (1.f + __expf(-x)); }
__device__ __forceinline__ float tanh_f(float x) { return 1.f - 2.f / (1.f + __expf(2.f * x)); }

// fp32 -> bf16 hi (RNE-ish) + bf16 lo of the residual.
__device__ __forceinline__ void bsplit(float a, unsigned short& h, unsigned short& l) {
    const unsigned int u  = __float_as_uint(a);
    const unsigned int hi = (u + 0x8000u) >> 16;
    const float fh = __uint_as_float(hi << 16);
    h = (unsigned short)hi;
    l = (unsigned short)(__float_as_uint(a - fh) >> 16);
}

// ---------------------------------------------------------------- prep ------
struct PrepArgs {
    const float* dwhh0; float* pk0;                   // kD L0 weights -> [k][hid][4]
    const float* d1x; const float* d1h; float* pack;  // kD dec L1 pack
    const float* bsrc[3];        // eWih1, eWhh0, eWhh1  (all [512][128] = [n][k])
    unsigned short* bh[3];
    unsigned short* bl[3];
};

__global__ void kPrep(PrepArgs a) {
    const int m = blockIdx.x;
    if (m == 0) {
        // pk0[(k*128 + j4)*4 + g] = dWhh0[j4+128g][k]  (gate-contiguous float4)
        for (int i = threadIdx.x; i < H_ * H_; i += blockDim.x) {
            const int k = i >> 7, j4 = i & 127;
            float* p = a.pk0 + ((size_t)k * H_ + j4) * 4;
#pragma unroll
            for (int g = 0; g < 4; g++)
                p[g] = a.dwhh0[(j4 + 128 * g) * H_ + k];
        }
    } else if (m == 1) {
        // pack[(k*128 + j4)*8 + g]   = dWih1[j4+128g][k]  (g=0..3)
        // pack[(k*128 + j4)*8 + 4+g] = dWhh1[j4+128g][k]
        for (int i = threadIdx.x; i < H_ * H_; i += blockDim.x) {
            const int k = i >> 7, j4 = i & 127;
            float* p = a.pack + ((size_t)k * H_ + j4) * 8;
#pragma unroll
            for (int g = 0; g < 4; g++) {
                p[g]     = a.d1x[(j4 + 128 * g) * H_ + k];
                p[4 + g] = a.d1h[(j4 + 128 * g) * H_ + k];
            }
        }
    } else {
        const int s = m - 2;
        const float* src = a.bsrc[s];
        unsigned short* dh = a.bh[s];
        unsigned short* dl = a.bl[s];
        for (int i = threadIdx.x; i < G_ * H_; i += blockDim.x) {
            unsigned short h, l;
            bsplit(src[i], h, l);
            dh[i] = h; dl[i] = l;
        }
    }
}

// ------------------- enc L0 body: MFMA recurrent, 16 batches ----------------
__device__ __forceinline__ void runL0(
    const float* __restrict__ feat,
    const unsigned short* __restrict__ WHh,
    const unsigned short* __restrict__ WHl,
    const float* __restrict__ wih0,
    const float* __restrict__ bias,
    unsigned short* __restrict__ Ah,
    unsigned short* __restrict__ Al,
    float* __restrict__ hS, float* __restrict__ cS,
    int t0, int CL, int bidx,
    unsigned short (*hh)[16][136], unsigned short (*hl)[16][136], float* fsh)
{
    const int tid  = threadIdx.x;
    const int lane = tid & 63;
    const int w    = tid >> 6;       // wave 0..7
    const int c15  = lane & 15;
    const int q    = lane >> 4;      // 0..3
    const int BG   = bidx * 16;

    // B-fragments: wave w's gates n = 16w + 128g + c15; k = 32kt + 8q + j.
    short8 wh[4][4], wl[4][4];
#pragma unroll
    for (int g = 0; g < 4; g++)
#pragma unroll
        for (int kt = 0; kt < 4; kt++) {
            const size_t off = (size_t)(16 * w + 128 * g + c15) * H_ + 32 * kt + 8 * q;
            wh[g][kt] = *(const short8*)(WHh + off);
            wl[g][kt] = *(const short8*)(WHl + off);
        }

    float bz[4], wx[4];
#pragma unroll
    for (int g = 0; g < 4; g++) {
        bz[g] = bias[16 * w + 128 * g + c15];
        wx[g] = wih0[16 * w + 128 * g + c15];
    }

    for (int i = tid; i < CL * 16; i += 512)
        fsh[i] = feat[(BG + (i & 15)) * T_ + t0 + (i >> 4)];

    float cc[4], hv[4];
#pragma unroll
    for (int r = 0; r < 4; r++) { cc[r] = 0.f; hv[r] = 0.f; }
    if (t0 != 0) {
#pragma unroll
        for (int r = 0; r < 4; r++) {
            const size_t si = (size_t)(BG + 4 * q + r) * H_ + 16 * w + c15;
            cc[r] = cS[si]; hv[r] = hS[si];
        }
    }
#pragma unroll
    for (int r = 0; r < 4; r++) {
        unsigned short hi, lo; bsplit(hv[r], hi, lo);
        hh[0][4 * q + r][16 * w + c15] = hi;
        hl[0][4 * q + r][16 * w + c15] = lo;
    }
    __syncthreads();

    int pb = 0;
    unsigned int hp[4];    // packed h(dt-1): hi | lo<<16, for deferred store

    for (int dt = 0; dt < CL; dt++) {
        if (dt > 0) {
#pragma unroll
            for (int r = 0; r < 4; r++) {
                const size_t ai = ((size_t)(dt - 1) * B_ + BG + 4 * q + r) * H_ + 16 * w + c15;
                Ah[ai] = (unsigned short)(hp[r] & 0xffffu);
                Al[ai] = (unsigned short)(hp[r] >> 16);
            }
        }

        floatx4 acc[4];
#pragma unroll
        for (int g = 0; g < 4; g++) acc[g] = (floatx4){0.f, 0.f, 0.f, 0.f};

#pragma unroll
        for (int kt = 0; kt < 4; kt++) {
            const short8 ahv = *(const short8*)&hh[pb][c15][32 * kt + 8 * q];
            const short8 alv = *(const short8*)&hl[pb][c15][32 * kt + 8 * q];
#pragma unroll
            for (int g = 0; g < 4; g++) {
                acc[g] = __builtin_amdgcn_mfma_f32_16x16x32_bf16(ahv, wh[g][kt], acc[g], 0, 0, 0);
                acc[g] = __builtin_amdgcn_mfma_f32_16x16x32_bf16(ahv, wl[g][kt], acc[g], 0, 0, 0);
                acc[g] = __builtin_amdgcn_mfma_f32_16x16x32_bf16(alv, wh[g][kt], acc[g], 0, 0, 0);
            }
        }

        const int nb = pb ^ 1;
#pragma unroll
        for (int r = 0; r < 4; r++) {
            const float x = fsh[dt * 16 + 4 * q + r];
            const float zi = acc[0][r] + __fmaf_rn(wx[0], x, bz[0]);
            const float zf = acc[1][r] + __fmaf_rn(wx[1], x, bz[1]);
            const float zg = acc[2][r] + __fmaf_rn(wx[2], x, bz[2]);
            const float zo = acc[3][r] + __fmaf_rn(wx[3], x, bz[3]);
            cc[r] = sigm(zf) * cc[r] + sigm(zi) * tanh_f(zg);
            const float h = sigm(zo) * tanh_f(cc[r]);
            hv[r] = h;
            unsigned short hi, lo; bsplit(h, hi, lo);
            hp[r] = (unsigned int)hi | ((unsigned int)lo << 16);
            hh[nb][4 * q + r][16 * w + c15] = hi;
            hl[nb][4 * q + r][16 * w + c15] = lo;
        }
        __syncthreads();
        pb = nb;
    }

#pragma unroll
    for (int r = 0; r < 4; r++) {
        const size_t ai = ((size_t)(CL - 1) * B_ + BG + 4 * q + r) * H_ + 16 * w + c15;
        Ah[ai] = (unsigned short)(hp[r] & 0xffffu);
        Al[ai] = (unsigned short)(hp[r] >> 16);
        const size_t si = (size_t)(BG + 4 * q + r) * H_ + 16 * w + c15;
        hS[si] = hv[r]; cS[si] = cc[r];
    }
}

// ------------------- enc L1 body: MFMA recurrent, 16 batches ----------------
__device__ __forceinline__ void runL1(
    const float* __restrict__ X1,
    const unsigned short* __restrict__ WHh,
    const unsigned short* __restrict__ WHl,
    float* __restrict__ hS, float* __restrict__ cS,
    int t0, int CL, int bidx,
    unsigned short (*hh)[16][136], unsigned short (*hl)[16][136])
{
    const int tid  = threadIdx.x;
    const int lane = tid & 63;
    const int w    = tid >> 6;
    const int c15  = lane & 15;
    const int q    = lane >> 4;
    const int BG   = bidx * 16;

    short8 wh[4][4], wl[4][4];
#pragma unroll
    for (int g = 0; g < 4; g++)
#pragma unroll
        for (int kt = 0; kt < 4; kt++) {
            const size_t off = (size_t)(16 * w + 128 * g + c15) * H_ + 32 * kt + 8 * q;
            wh[g][kt] = *(const short8*)(WHh + off);
            wl[g][kt] = *(const short8*)(WHl + off);
        }

    float cc[4], hv[4];
#pragma unroll
    for (int r = 0; r < 4; r++) { cc[r] = 0.f; hv[r] = 0.f; }
    if (t0 != 0) {
#pragma unroll
        for (int r = 0; r < 4; r++) {
            const size_t si = (size_t)(BG + 4 * q + r) * H_ + 16 * w + c15;
            cc[r] = cS[si]; hv[r] = hS[si];
        }
    }
#pragma unroll
    for (int r = 0; r < 4; r++) {
        unsigned short hi, lo; bsplit(hv[r], hi, lo);
        hh[0][4 * q + r][16 * w + c15] = hi;
        hl[0][4 * q + r][16 * w + c15] = lo;
    }
    __syncthreads();

    int pb = 0;

    for (int dt = 0; dt < CL; dt++) {
        float x1v[4][4];
#pragma unroll
        for (int g = 0; g < 4; g++)
#pragma unroll
            for (int r = 0; r < 4; r++)
                x1v[g][r] = X1[((size_t)dt * B_ + BG + 4 * q + r) * G_ + 16 * w + 128 * g + c15];

        floatx4 acc[4];
#pragma unroll
        for (int g = 0; g < 4; g++) acc[g] = (floatx4){0.f, 0.f, 0.f, 0.f};

#pragma unroll
        for (int kt = 0; kt < 4; kt++) {
            const short8 ahv = *(const short8*)&hh[pb][c15][32 * kt + 8 * q];
            const short8 alv = *(const short8*)&hl[pb][c15][32 * kt + 8 * q];
#pragma unroll
            for (int g = 0; g < 4; g++) {
                acc[g] = __builtin_amdgcn_mfma_f32_16x16x32_bf16(ahv, wh[g][kt], acc[g], 0, 0, 0);
                acc[g] = __builtin_amdgcn_mfma_f32_16x16x32_bf16(ahv, wl[g][kt], acc[g], 0, 0, 0);
                acc[g] = __builtin_amdgcn_mfma_f32_16x16x32_bf16(alv, wh[g][kt], acc[g], 0, 0, 0);
            }
        }

        const int nb = pb ^ 1;
#pragma unroll
        for (int r = 0; r < 4; r++) {
            const float zi = acc[0][r] + x1v[0][r];
            const float zf = acc[1][r] + x1v[1][r];
            const float zg = acc[2][r] + x1v[2][r];
            const float zo = acc[3][r] + x1v[3][r];
            cc[r] = sigm(zf) * cc[r] + sigm(zi) * tanh_f(zg);
            const float h = sigm(zo) * tanh_f(cc[r]);
            hv[r] = h;
            unsigned short hi, lo; bsplit(h, hi, lo);
            hh[nb][4 * q + r][16 * w + c15] = hi;
            hl[nb][4 * q + r][16 * w + c15] = lo;
        }
        __syncthreads();
        pb = nb;
    }

#pragma unroll
    for (int r = 0; r < 4; r++) {
        const size_t si = (size_t)(BG + 4 * q + r) * H_ + 16 * w + c15;
        hS[si] = hv[r]; cS[si] = cc[r];
    }
}

// ---------------- fused pipeline launch: L0(chunk c) || L1(chunk c-1) -------
__global__ __launch_bounds__(512, 2) void kF(
    const float* __restrict__ feat,
    const unsigned short* __restrict__ H0h, const unsigned short* __restrict__ H0l,
    const float* __restrict__ wih0, const float* __restrict__ bias0,
    unsigned short* __restrict__ Ah, unsigned short* __restrict__ Al,
    float* __restrict__ h1S, float* __restrict__ c1S,
    const float* __restrict__ X1,
    const unsigned short* __restrict__ H1h, const unsigned short* __restrict__ H1l,
    float* __restrict__ h2S, float* __restrict__ c2S,
    int c, int CL, int NC)
{
    __shared__ __align__(16) unsigned short hh[2][16][136];
    __shared__ __align__(16) unsigned short hl[2][16][136];
    __shared__ __align__(16) float fsh[672];

    if (blockIdx.x < 64) {
        if (c < NC)
            runL0(feat, H0h, H0l, wih0, bias0, Ah, Al, h1S, c1S,
                  c * CL, CL, blockIdx.x, hh, hl, fsh);
    } else {
        if (c > 0)
            runL1(X1, H1h, H1l, h2S, c2S,
                  (c - 1) * CL, CL, blockIdx.x - 64, hh, hl);
    }
}

// ----------------------- X1 GEMM via MFMA bf16 split-2 ----------------------
__global__ __launch_bounds__(256, 2) void kXm(
    const unsigned short* __restrict__ Ah,  // [CL][1024][128]
    const unsigned short* __restrict__ Al,
    const unsigned short* __restrict__ Wh,  // [512][128]
    const unsigned short* __restrict__ Wl,
    const float* __restrict__ bias,         // [512]
    float* __restrict__ X1)                 // [CL][1024][512]
{
    __shared__ __align__(16) unsigned short Bh[128 * 128];
    __shared__ __align__(16) unsigned short Bl[128 * 128];

    const int tid = threadIdx.x;
    const int n0  = blockIdx.y * 128;

    for (int c = tid; c < 2048; c += 256) {
        const int n  = c >> 4;
        const int kb = (c & 15) << 4;
        const int sb = n * 256 + (kb ^ ((n & 7) << 4));
        *(float4*)((char*)Bh + sb) =
            *(const float4*)((const char*)Wh + (size_t)(n0 + n) * 256 + kb);
        *(float4*)((char*)Bl + sb) =
            *(const float4*)((const char*)Wl + (size_t)(n0 + n) * 256 + kb);
    }
    __syncthreads();

    const int lane = tid & 63;
    const int w    = tid >> 6;
    const int l15  = lane & 15;
    const int lq   = lane >> 4;
    const int dt   = blockIdx.z;
    const int m0   = blockIdx.x * 128 + w * 32;

    const size_t arow = ((size_t)dt * B_ + m0 + l15) * H_;
    const unsigned short* a0h = Ah + arow;
    const unsigned short* a0l = Al + arow;

    floatx4 acc[2][8];
#pragma unroll
    for (int i = 0; i < 2; i++)
#pragma unroll
        for (int j = 0; j < 8; j++)
            acc[i][j] = (floatx4){0.f, 0.f, 0.f, 0.f};

#pragma unroll
    for (int ks = 0; ks < 4; ks++) {
        const int kk = ks * 32 + 8 * lq;
        const short8 ah0 = *(const short8*)(a0h + kk);
        const short8 al0 = *(const short8*)(a0l + kk);
        const short8 ah1 = *(const short8*)(a0h + 16 * H_ + kk);
        const short8 al1 = *(const short8*)(a0l + 16 * H_ + kk);
        const int kbb = kk * 2;
#pragma unroll
        for (int nt = 0; nt < 8; nt++) {
            const int row = nt * 16 + l15;
            const int sb  = row * 256 + (kbb ^ ((row & 7) << 4));
            const short8 bh = *(const short8*)((const char*)Bh + sb);
            const short8 bl = *(const short8*)((const char*)Bl + sb);
            acc[0][nt] = __builtin_amdgcn_mfma_f32_16x16x32_bf16(ah0, bh, acc[0][nt], 0, 0, 0);
            acc[1][nt] = __builtin_amdgcn_mfma_f32_16x16x32_bf16(ah1, bh, acc[1][nt], 0, 0, 0);
            acc[0][nt] = __builtin_amdgcn_mfma_f32_16x16x32_bf16(ah0, bl, acc[0][nt], 0, 0, 0);
            acc[1][nt] = __builtin_amdgcn_mfma_f32_16x16x32_bf16(ah1, bl, acc[1][nt], 0, 0, 0);
            acc[0][nt] = __builtin_amdgcn_mfma_f32_16x16x32_bf16(al0, bh, acc[0][nt], 0, 0, 0);
            acc[1][nt] = __builtin_amdgcn_mfma_f32_16x16x32_bf16(al1, bh, acc[1][nt], 0, 0, 0);
        }
    }

#pragma unroll
    for (int nt = 0; nt < 8; nt++) {
        const float bv = bias[n0 + nt * 16 + l15];
#pragma unroll
        for (int mt = 0; mt < 2; mt++) {
            const size_t orow =
                ((size_t)dt * B_ + m0 + mt * 16 + lq * 4) * G_ + n0 + nt * 16 + l15;
#pragma unroll
            for (int r = 0; r < 4; r++)
                X1[orow + (size_t)r * G_] = acc[mt][nt][r] + bv;
        }
    }
}

// ------------------------------------------- decoder (quad-gate both dots) --
__global__ __launch_bounds__(512, 2) void kD(
    const float* __restrict__ h1S, const float* __restrict__ c1S,
    const float* __restrict__ h2S, const float* __restrict__ c2S,
    const float* __restrict__ whh0P,  // [128][128][4] dec_Whh0 gate-packed (L2 stream)
    const float* __restrict__ wih0,   // [512]
    const float* __restrict__ b0,
    const float* __restrict__ packD1, // [128][128][8]
    const float* __restrict__ b1,
    const float* __restrict__ wo1,    // [128][128] W_out1 [hid][k] -> LDS rows
    const float* __restrict__ bo1,
    const float* __restrict__ wo2,
    const float* __restrict__ bo2,
    float* __restrict__ out)          // [B,TGT]
{
    __shared__ __align__(16) float h1_sh[H_ * 4];
    __shared__ __align__(16) float h2_sh[H_ * 4];
    __shared__ __align__(16) float h2t[4][H_];       // [bb][hid]
    __shared__ __align__(16) float zp[4 * 2048];
    __shared__ __align__(16) float wo1s[H_ * 132];   // rows [hid][k], pad 132
    __shared__ float rp[8];

    const int tid = threadIdx.x;
    const int hid = tid & 127;        // gate group / act hid
    const int bb  = tid >> 7;         // k-quarter / act batch
    const int B0  = blockIdx.x * 4;

    const float b0i = b0[hid],        b0f = b0[hid + 128];
    const float b0g = b0[hid + 256],  b0o = b0[hid + 384];
    const float wxi = wih0[hid],      wxf = wih0[hid + 128];
    const float wxg = wih0[hid + 256], wxo = wih0[hid + 384];
    const float b1i = b1[hid],        b1f = b1[hid + 128];
    const float b1g = b1[hid + 256],  b1o = b1[hid + 384];

    for (int t = tid; t < H_ * 32; t += 512) {
        const int r = t >> 5, q = t & 31;
        *(float4*)&wo1s[r * 132 + q * 4] = *(const float4*)&wo1[r * H_ + q * 4];
    }

    const float wo2v = wo2[hid];
    const float bo1j = bo1[hid];
    const float bo2v = bo2[0];

    float c1 = c1S[(B0 + bb) * H_ + hid];
    float c2 = c2S[(B0 + bb) * H_ + hid];
    h1_sh[hid * 4 + bb] = h1S[(B0 + bb) * H_ + hid];
    {
        const float h2v = h2S[(B0 + bb) * H_ + hid];
        h2_sh[hid * 4 + bb] = h2v;
        h2t[bb][hid] = h2v;
    }
    if (tid < 8) rp[tid] = -0.5f * bo2v;   // so pred(step 0) = 0
    __syncthreads();

    const float* hb1 = h1_sh + bb * 128;
    const float* hb2 = h2_sh + bb * 128;
    const float* pk  = packD1 + ((size_t)bb * 32 * H_ + hid) * 8;
    const float* pw0 = whh0P + (size_t)bb * 32 * 512 + hid * 4;   // [k][hid][4] slice

    for (int s = 0; s < TGT_; s++) {
        // ===== phase 1: L0 h-dot (L2 weight stream) + head of h2(s-1) =====
        {
            float a[4][4] = {};
#pragma unroll 8
            for (int k = 0; k < 32; k++) {
                const float4 wv = *(const float4*)&pw0[(size_t)k * 512];  // gates i,f,g,o
                const float4 h4 = *(const float4*)&hb1[k * 4];
                a[0][0] = __fmaf_rn(h4.x, wv.x, a[0][0]);
                a[0][1] = __fmaf_rn(h4.y, wv.x, a[0][1]);
                a[0][2] = __fmaf_rn(h4.z, wv.x, a[0][2]);
                a[0][3] = __fmaf_rn(h4.w, wv.x, a[0][3]);
                a[1][0] = __fmaf_rn(h4.x, wv.y, a[1][0]);
                a[1][1] = __fmaf_rn(h4.y, wv.y, a[1][1]);
                a[1][2] = __fmaf_rn(h4.z, wv.y, a[1][2]);
                a[1][3] = __fmaf_rn(h4.w, wv.y, a[1][3]);
                a[2][0] = __fmaf_rn(h4.x, wv.z, a[2][0]);
                a[2][1] = __fmaf_rn(h4.y, wv.z, a[2][1]);
                a[2][2] = __fmaf_rn(h4.z, wv.z, a[2][2]);
                a[2][3] = __fmaf_rn(h4.w, wv.z, a[2][3]);
                a[3][0] = __fmaf_rn(h4.x, wv.w, a[3][0]);
                a[3][1] = __fmaf_rn(h4.y, wv.w, a[3][1]);
                a[3][2] = __fmaf_rn(h4.z, wv.w, a[3][2]);
                a[3][3] = __fmaf_rn(h4.w, wv.w, a[3][3]);
            }
#pragma unroll
            for (int g = 0; g < 4; g++)
#pragma unroll
                for (int b = 0; b < 4; b++)
                    zp[bb * 2048 + b * 512 + hid + 128 * g] = a[g][b];
        }
        {
            float hacc = bo1j;
#pragma unroll
            for (int q = 0; q < 32; q++) {
                const float4 hq = *(const float4*)&h2t[bb][q * 4];          // uniform
                const float4 wq = *(const float4*)&wo1s[hid * 132 + q * 4]; // lane-spread
                hacc = __fmaf_rn(hq.x, wq.x, hacc);
                hacc = __fmaf_rn(hq.y, wq.y, hacc);
                hacc = __fmaf_rn(hq.z, wq.z, hacc);
                hacc = __fmaf_rn(hq.w, wq.w, hacc);
            }
            float p = fmaxf(hacc, 0.f) * wo2v;
            p += __shfl_down(p, 32); p += __shfl_down(p, 16); p += __shfl_down(p, 8);
            p += __shfl_down(p, 4);  p += __shfl_down(p, 2);  p += __shfl_down(p, 1);
            if ((tid & 63) == 0) rp[tid >> 6] = p;
        }
        __syncthreads();

        // ===== phase 2: L0 act (+ x-term via pred), out write =====
        {
            const float pred = rp[2 * bb] + rp[2 * bb + 1] + bo2v;
            if (hid == 0 && s > 0) out[(B0 + bb) * TGT_ + (s - 1)] = pred;
            const int base = bb * 512 + hid;
            float zi = __fmaf_rn(wxi, pred, b0i);
            float zf = __fmaf_rn(wxf, pred, b0f);
            float zg = __fmaf_rn(wxg, pred, b0g);
            float zo = __fmaf_rn(wxo, pred, b0o);
#pragma unroll
            for (int q = 0; q < 4; q++) {
                zi += zp[q * 2048 + base];
                zf += zp[q * 2048 + base + 128];
                zg += zp[q * 2048 + base + 256];
                zo += zp[q * 2048 + base + 384];
            }
            c1 = sigm(zf) * c1 + sigm(zi) * tanh_f(zg);
            h1_sh[hid * 4 + bb] = sigm(zo) * tanh_f(c1);
        }
        __syncthreads();

        // ===== phase 3: L1 dot (L2 stream: 32 contiguous B per thread per k) =====
        {
            float d[4][4] = {};
#pragma unroll 8
            for (int k = 0; k < 32; k++) {
                const float4 wi = *(const float4*)&pk[(size_t)k * 1024];
                const float4 wh = *(const float4*)&pk[(size_t)k * 1024 + 4];
                const float4 p1 = *(const float4*)&hb1[k * 4];
                const float4 p2 = *(const float4*)&hb2[k * 4];
                d[0][0] = __fmaf_rn(p1.x, wi.x, __fmaf_rn(p2.x, wh.x, d[0][0]));
                d[0][1] = __fmaf_rn(p1.y, wi.x, __fmaf_rn(p2.y, wh.x, d[0][1]));
                d[0][2] = __fmaf_rn(p1.z, wi.x, __fmaf_rn(p2.z, wh.x, d[0][2]));
                d[0][3] = __fmaf_rn(p1.w, wi.x, __fmaf_rn(p2.w, wh.x, d[0][3]));
                d[1][0] = __fmaf_rn(p1.x, wi.y, __fmaf_rn(p2.x, wh.y, d[1][0]));
                d[1][1] = __fmaf_rn(p1.y, wi.y, __fmaf_rn(p2.y, wh.y, d[1][1]));
                d[1][2] = __fmaf_rn(p1.z, wi.y, __fmaf_rn(p2.z, wh.y, d[1][2]));
                d[1][3] = __fmaf_rn(p1.w, wi.y, __fmaf_rn(p2.w, wh.y, d[1][3]));
                d[2][0] = __fmaf_rn(p1.x, wi.z, __fmaf_rn(p2.x, wh.z, d[2][0]));
                d[2][1] = __fmaf_rn(p1.y, wi.z, __fmaf_rn(p2.y, wh.z, d[2][1]));
                d[2][2] = __fmaf_rn(p1.z, wi.z, __fmaf_rn(p2.z, wh.z, d[2][2]));
                d[2][3] = __fmaf_rn(p1.w, wi.z, __fmaf_rn(p2.w, wh.z, d[2][3]));
                d[3][0] = __fmaf_rn(p1.x, wi.w, __fmaf_rn(p2.x, wh.w, d[3][0]));
                d[3][1] = __fmaf_rn(p1.y, wi.w, __fmaf_rn(p2.y, wh.w, d[3][1]));
                d[3][2] = __fmaf_rn(p1.z, wi.w, __fmaf_rn(p2.z, wh.w, d[3][2]));
                d[3][3] = __fmaf_rn(p1.w, wi.w, __fmaf_rn(p2.w, wh.w, d[3][3]));
            }
#pragma unroll
            for (int g = 0; g < 4; g++)
#pragma unroll
                for (int b = 0; b < 4; b++)
                    zp[bb * 2048 + b * 512 + hid + 128 * g] = d[g][b];
        }
        __syncthreads();

        // ===== phase 4: L1 act =====
        {
            const int base = bb * 512 + hid;
            float zi = b1i, zf = b1f, zg = b1g, zo = b1o;
#pragma unroll
            for (int q = 0; q < 4; q++) {
                zi += zp[q * 2048 + base];
                zf += zp[q * 2048 + base + 128];
                zg += zp[q * 2048 + base + 256];
                zo += zp[q * 2048 + base + 384];
            }
            c2 = sigm(zf) * c2 + sigm(zi) * tanh_f(zg);
            const float h2v = sigm(zo) * tanh_f(c2);
            h2_sh[hid * 4 + bb] = h2v;
            h2t[bb][hid] = h2v;
        }
        __syncthreads();
    }

    // ===== epilogue: head of final h2 -> out[..][95] =====
    {
        float hacc = bo1j;
#pragma unroll
        for (int q = 0; q < 32; q++) {
            const float4 hq = *(const float4*)&h2t[bb][q * 4];
            const float4 wq = *(const float4*)&wo1s[hid * 132 + q * 4];
            hacc = __fmaf_rn(hq.x, wq.x, hacc);
            hacc = __fmaf_rn(hq.y, wq.y, hacc);
            hacc = __fmaf_rn(hq.z, wq.z, hacc);
            hacc = __fmaf_rn(hq.w, wq.w, hacc);
        }
        float p = fmaxf(hacc, 0.f) * wo2v;
        p += __shfl_down(p, 32); p += __shfl_down(p, 16); p += __shfl_down(p, 8);
        p += __shfl_down(p, 4);  p += __shfl_down(p, 2);  p += __shfl_down(p, 1);
        if ((tid & 63) == 0) rp[tid >> 6] = p;
    }
    __syncthreads();
    if (tid < 4)
        out[(B0 + tid) * TGT_ + (TGT_ - 1)] = rp[2 * tid] + rp[2 * tid + 1] + bo2v;
}

// ---------------------------------------------------------------- launch ----
extern "C" void kernel_launch(void* const* d_in, const int* in_sizes, int n_in,
                              void* d_out, int out_size, void* d_ws, size_t ws_size,
                              hipStream_t stream) {
    const float* feat  = (const float*)d_in[0];
    const float* eWih0 = (const float*)d_in[1];
    const float* eWhh0 = (const float*)d_in[2];
    const float* eB0   = (const float*)d_in[3];
    const float* eWih1 = (const float*)d_in[4];
    const float* eWhh1 = (const float*)d_in[5];
    const float* eB1   = (const float*)d_in[6];
    const float* dWih0 = (const float*)d_in[7];
    const float* dWhh0 = (const float*)d_in[8];
    const float* dB0   = (const float*)d_in[9];
    const float* dWih1 = (const float*)d_in[10];
    const float* dWhh1 = (const float*)d_in[11];
    const float* dB1   = (const float*)d_in[12];
    const float* Wo1   = (const float*)d_in[13];
    const float* bo1   = (const float*)d_in[14];
    const float* Wo2   = (const float*)d_in[15];
    const float* bo2   = (const float*)d_in[16];

    const size_t SZ_BH = (size_t)B_ * H_;     // 131072
    const size_t SZ_W  = (size_t)G_ * H_;     // 65536
    const size_t fixed_f = 4 * SZ_BH + 6 * SZ_W + 64;

    // CL <= 42 so X1 + A-halves stay L3-resident
    static const int cands[] = {42, 32, 28, 24, 21, 16, 14, 12, 8, 7, 6, 4, 3, 2, 1};
    int CL = 1;
    for (int ci = 0; ci < 15; ci++) {
        const size_t need = (fixed_f + (size_t)cands[ci] * B_ * (H_ + G_)) * 4;
        if (need <= ws_size) { CL = cands[ci]; break; }
    }
    const int NC = T_ / CL;

    float* ws = (float*)d_ws;
    unsigned short* Ah = (unsigned short*)ws;            // [CL][1024][128] bf16-hi
    unsigned short* Al = Ah + (size_t)CL * B_ * H_;      // [CL][1024][128] bf16-lo
    float* X1    = ws + (size_t)CL * B_ * H_;            // [CL][1024][512]
    float* h1S   = X1 + (size_t)CL * B_ * G_;
    float* c1S   = h1S + SZ_BH;
    float* h2S   = c1S + SZ_BH;
    float* c2S   = h2S + SZ_BH;
    float* pk0   = c2S + SZ_BH;                          // [128][128][4] (SZ_W floats)
    float* wtD1p = pk0 + SZ_W;                           // [128][128][8] = 2*SZ_W
    unsigned short* Wh  = (unsigned short*)(wtD1p + 2 * SZ_W);  // eWih1 split
    unsigned short* Wl  = Wh + SZ_W;
    unsigned short* H0h = Wl + SZ_W;                            // eWhh0 split
    unsigned short* H0l = H0h + SZ_W;
    unsigned short* H1h = H0l + SZ_W;                           // eWhh1 split
    unsigned short* H1l = H1h + SZ_W;

    PrepArgs pa;
    pa.dwhh0 = dWhh0; pa.pk0 = pk0;
    pa.d1x = dWih1; pa.d1h = dWhh1; pa.pack = wtD1p;
    pa.bsrc[0] = eWih1; pa.bh[0] = Wh;  pa.bl[0] = Wl;
    pa.bsrc[1] = eWhh0; pa.bh[1] = H0h; pa.bl[1] = H0l;
    pa.bsrc[2] = eWhh1; pa.bh[2] = H1h; pa.bl[2] = H1l;
    kPrep<<<5, 256, 0, stream>>>(pa);

    // Pipelined: F(c) = L0(chunk c) on blocks 0-63  ||  L1(chunk c-1) on 64-127.
    // Stream order: kXm(c-1) < F(c) < kXm(c)  provides all dependencies.
    for (int c = 0; c <= NC; c++) {
        kF<<<128, 512, 0, stream>>>(feat, H0h, H0l, eWih0, eB0, Ah, Al, h1S, c1S,
                                    X1, H1h, H1l, h2S, c2S, c, CL, NC);
        if (c < NC)
            kXm<<<dim3(8, 4, CL), 256, 0, stream>>>(Ah, Al, Wh, Wl, eB1, X1);
    }
    kD<<<NBLK_, 512, 0, stream>>>(h1S, c1S, h2S, c2S,
                                  pk0, dWih0, dB0,
                                  wtD1p, dB1,
                                  Wo1, bo1, Wo2, bo2,
                                  (float*)d_out);
}

// Round 6
// 2837.335 us; speedup vs baseline: 1.6494x; 1.1586x over previous
//
#include <hip/hip_runtime.h>

// Seq2SeqLSTMForecaster on MI355X — round 16.
// R15 confirmed chunk-pipelining (4679->3287). Ledger: kF 1650us (128/256
// CUs), kD 1010us, kXm 600us serialized. This round: depth-3 pipeline —
// fold the X1 GEMM into kF's idle 128 CUs. kF(c) = L0(c) | GEMM(c-1) |
// L1(c-2); all deps are stream-order across launches; races removed by
// parity double-buffering A and X1 (no atomics). GEMM is fragment- and
// order-identical to kXm -> X1 bit-identical -> absmax unchanged.
//  runL0/runL1/kD/kPrep: byte-identical to round 15.

#define B_    1024
#define T_    672
#define H_    128
#define G_    512      // 4*H
#define TGT_  96
#define NBLK_ 256

typedef __attribute__((ext_vector_type(8))) short  short8;
typedef __attribute__((ext_vector_type(4))) float  floatx4;

__device__ __forceinline__ float sigm(float x)   { return 1.f / (1.f + __expf(-x)); }
__device__ __forceinline__ float tanh_f(float x) { return 1.f - 2.f / (1.f + __expf(2.f * x)); }

// fp32 -> bf16 hi (RNE-ish) + bf16 lo of the residual.
__device__ __forceinline__ void bsplit(float a, unsigned short& h, unsigned short& l) {
    const unsigned int u  = __float_as_uint(a);
    const unsigned int hi = (u + 0x8000u) >> 16;
    const float fh = __uint_as_float(hi << 16);
    h = (unsigned short)hi;
    l = (unsigned short)(__float_as_uint(a - fh) >> 16);
}

// ---------------------------------------------------------------- prep ------
struct PrepArgs {
    const float* dwhh0; float* pk0;                   // kD L0 weights -> [k][hid][4]
    const float* d1x; const float* d1h; float* pack;  // kD dec L1 pack
    const float* bsrc[3];        // eWih1, eWhh0, eWhh1  (all [512][128] = [n][k])
    unsigned short* bh[3];
    unsigned short* bl[3];
};

__global__ void kPrep(PrepArgs a) {
    const int m = blockIdx.x;
    if (m == 0) {
        // pk0[(k*128 + j4)*4 + g] = dWhh0[j4+128g][k]  (gate-contiguous float4)
        for (int i = threadIdx.x; i < H_ * H_; i += blockDim.x) {
            const int k = i >> 7, j4 = i & 127;
            float* p = a.pk0 + ((size_t)k * H_ + j4) * 4;
#pragma unroll
            for (int g = 0; g < 4; g++)
                p[g] = a.dwhh0[(j4 + 128 * g) * H_ + k];
        }
    } else if (m == 1) {
        // pack[(k*128 + j4)*8 + g]   = dWih1[j4+128g][k]  (g=0..3)
        // pack[(k*128 + j4)*8 + 4+g] = dWhh1[j4+128g][k]
        for (int i = threadIdx.x; i < H_ * H_; i += blockDim.x) {
            const int k = i >> 7, j4 = i & 127;
            float* p = a.pack + ((size_t)k * H_ + j4) * 8;
#pragma unroll
            for (int g = 0; g < 4; g++) {
                p[g]     = a.d1x[(j4 + 128 * g) * H_ + k];
                p[4 + g] = a.d1h[(j4 + 128 * g) * H_ + k];
            }
        }
    } else {
        const int s = m - 2;
        const float* src = a.bsrc[s];
        unsigned short* dh = a.bh[s];
        unsigned short* dl = a.bl[s];
        for (int i = threadIdx.x; i < G_ * H_; i += blockDim.x) {
            unsigned short h, l;
            bsplit(src[i], h, l);
            dh[i] = h; dl[i] = l;
        }
    }
}

// ------------------- enc L0 body: MFMA recurrent, 16 batches ----------------
__device__ __forceinline__ void runL0(
    const float* __restrict__ feat,
    const unsigned short* __restrict__ WHh,
    const unsigned short* __restrict__ WHl,
    const float* __restrict__ wih0,
    const float* __restrict__ bias,
    unsigned short* __restrict__ Ah,
    unsigned short* __restrict__ Al,
    float* __restrict__ hS, float* __restrict__ cS,
    int t0, int CL, int bidx,
    unsigned short (*hh)[16][136], unsigned short (*hl)[16][136], float* fsh)
{
    const int tid  = threadIdx.x;
    const int lane = tid & 63;
    const int w    = tid >> 6;       // wave 0..7
    const int c15  = lane & 15;
    const int q    = lane >> 4;      // 0..3
    const int BG   = bidx * 16;

    // B-fragments: wave w's gates n = 16w + 128g + c15; k = 32kt + 8q + j.
    short8 wh[4][4], wl[4][4];
#pragma unroll
    for (int g = 0; g < 4; g++)
#pragma unroll
        for (int kt = 0; kt < 4; kt++) {
            const size_t off = (size_t)(16 * w + 128 * g + c15) * H_ + 32 * kt + 8 * q;
            wh[g][kt] = *(const short8*)(WHh + off);
            wl[g][kt] = *(const short8*)(WHl + off);
        }

    float bz[4], wx[4];
#pragma unroll
    for (int g = 0; g < 4; g++) {
        bz[g] = bias[16 * w + 128 * g + c15];
        wx[g] = wih0[16 * w + 128 * g + c15];
    }

    for (int i = tid; i < CL * 16; i += 512)
        fsh[i] = feat[(BG + (i & 15)) * T_ + t0 + (i >> 4)];

    float cc[4], hv[4];
#pragma unroll
    for (int r = 0; r < 4; r++) { cc[r] = 0.f; hv[r] = 0.f; }
    if (t0 != 0) {
#pragma unroll
        for (int r = 0; r < 4; r++) {
            const size_t si = (size_t)(BG + 4 * q + r) * H_ + 16 * w + c15;
            cc[r] = cS[si]; hv[r] = hS[si];
        }
    }
#pragma unroll
    for (int r = 0; r < 4; r++) {
        unsigned short hi, lo; bsplit(hv[r], hi, lo);
        hh[0][4 * q + r][16 * w + c15] = hi;
        hl[0][4 * q + r][16 * w + c15] = lo;
    }
    __syncthreads();

    int pb = 0;
    unsigned int hp[4];    // packed h(dt-1): hi | lo<<16, for deferred store

    for (int dt = 0; dt < CL; dt++) {
        if (dt > 0) {
#pragma unroll
            for (int r = 0; r < 4; r++) {
                const size_t ai = ((size_t)(dt - 1) * B_ + BG + 4 * q + r) * H_ + 16 * w + c15;
                Ah[ai] = (unsigned short)(hp[r] & 0xffffu);
                Al[ai] = (unsigned short)(hp[r] >> 16);
            }
        }

        floatx4 acc[4];
#pragma unroll
        for (int g = 0; g < 4; g++) acc[g] = (floatx4){0.f, 0.f, 0.f, 0.f};

#pragma unroll
        for (int kt = 0; kt < 4; kt++) {
            const short8 ahv = *(const short8*)&hh[pb][c15][32 * kt + 8 * q];
            const short8 alv = *(const short8*)&hl[pb][c15][32 * kt + 8 * q];
#pragma unroll
            for (int g = 0; g < 4; g++) {
                acc[g] = __builtin_amdgcn_mfma_f32_16x16x32_bf16(ahv, wh[g][kt], acc[g], 0, 0, 0);
                acc[g] = __builtin_amdgcn_mfma_f32_16x16x32_bf16(ahv, wl[g][kt], acc[g], 0, 0, 0);
                acc[g] = __builtin_amdgcn_mfma_f32_16x16x32_bf16(alv, wh[g][kt], acc[g], 0, 0, 0);
            }
        }

        const int nb = pb ^ 1;
#pragma unroll
        for (int r = 0; r < 4; r++) {
            const float x = fsh[dt * 16 + 4 * q + r];
            const float zi = acc[0][r] + __fmaf_rn(wx[0], x, bz[0]);
            const float zf = acc[1][r] + __fmaf_rn(wx[1], x, bz[1]);
            const float zg = acc[2][r] + __fmaf_rn(wx[2], x, bz[2]);
            const float zo = acc[3][r] + __fmaf_rn(wx[3], x, bz[3]);
            cc[r] = sigm(zf) * cc[r] + sigm(zi) * tanh_f(zg);
            const float h = sigm(zo) * tanh_f(cc[r]);
            hv[r] = h;
            unsigned short hi, lo; bsplit(h, hi, lo);
            hp[r] = (unsigned int)hi | ((unsigned int)lo << 16);
            hh[nb][4 * q + r][16 * w + c15] = hi;
            hl[nb][4 * q + r][16 * w + c15] = lo;
        }
        __syncthreads();
        pb = nb;
    }

#pragma unroll
    for (int r = 0; r < 4; r++) {
        const size_t ai = ((size_t)(CL - 1) * B_ + BG + 4 * q + r) * H_ + 16 * w + c15;
        Ah[ai] = (unsigned short)(hp[r] & 0xffffu);
        Al[ai] = (unsigned short)(hp[r] >> 16);
        const size_t si = (size_t)(BG + 4 * q + r) * H_ + 16 * w + c15;
        hS[si] = hv[r]; cS[si] = cc[r];
    }
}

// ------------------- enc L1 body: MFMA recurrent, 16 batches ----------------
__device__ __forceinline__ void runL1(
    const float* __restrict__ X1,
    const unsigned short* __restrict__ WHh,
    const unsigned short* __restrict__ WHl,
    float* __restrict__ hS, float* __restrict__ cS,
    int t0, int CL, int bidx,
    unsigned short (*hh)[16][136], unsigned short (*hl)[16][136])
{
    const int tid  = threadIdx.x;
    const int lane = tid & 63;
    const int w    = tid >> 6;
    const int c15  = lane & 15;
    const int q    = lane >> 4;
    const int BG   = bidx * 16;

    short8 wh[4][4], wl[4][4];
#pragma unroll
    for (int g = 0; g < 4; g++)
#pragma unroll
        for (int kt = 0; kt < 4; kt++) {
            const size_t off = (size_t)(16 * w + 128 * g + c15) * H_ + 32 * kt + 8 * q;
            wh[g][kt] = *(const short8*)(WHh + off);
            wl[g][kt] = *(const short8*)(WHl + off);
        }

    float cc[4], hv[4];
#pragma unroll
    for (int r = 0; r < 4; r++) { cc[r] = 0.f; hv[r] = 0.f; }
    if (t0 != 0) {
#pragma unroll
        for (int r = 0; r < 4; r++) {
            const size_t si = (size_t)(BG + 4 * q + r) * H_ + 16 * w + c15;
            cc[r] = cS[si]; hv[r] = hS[si];
        }
    }
#pragma unroll
    for (int r = 0; r < 4; r++) {
        unsigned short hi, lo; bsplit(hv[r], hi, lo);
        hh[0][4 * q + r][16 * w + c15] = hi;
        hl[0][4 * q + r][16 * w + c15] = lo;
    }
    __syncthreads();

    int pb = 0;

    for (int dt = 0; dt < CL; dt++) {
        float x1v[4][4];
#pragma unroll
        for (int g = 0; g < 4; g++)
#pragma unroll
            for (int r = 0; r < 4; r++)
                x1v[g][r] = X1[((size_t)dt * B_ + BG + 4 * q + r) * G_ + 16 * w + 128 * g + c15];

        floatx4 acc[4];
#pragma unroll
        for (int g = 0; g < 4; g++) acc[g] = (floatx4){0.f, 0.f, 0.f, 0.f};

#pragma unroll
        for (int kt = 0; kt < 4; kt++) {
            const short8 ahv = *(const short8*)&hh[pb][c15][32 * kt + 8 * q];
            const short8 alv = *(const short8*)&hl[pb][c15][32 * kt + 8 * q];
#pragma unroll
            for (int g = 0; g < 4; g++) {
                acc[g] = __builtin_amdgcn_mfma_f32_16x16x32_bf16(ahv, wh[g][kt], acc[g], 0, 0, 0);
                acc[g] = __builtin_amdgcn_mfma_f32_16x16x32_bf16(ahv, wl[g][kt], acc[g], 0, 0, 0);
                acc[g] = __builtin_amdgcn_mfma_f32_16x16x32_bf16(alv, wh[g][kt], acc[g], 0, 0, 0);
            }
        }

        const int nb = pb ^ 1;
#pragma unroll
        for (int r = 0; r < 4; r++) {
            const float zi = acc[0][r] + x1v[0][r];
            const float zf = acc[1][r] + x1v[1][r];
            const float zg = acc[2][r] + x1v[2][r];
            const float zo = acc[3][r] + x1v[3][r];
            cc[r] = sigm(zf) * cc[r] + sigm(zi) * tanh_f(zg);
            const float h = sigm(zo) * tanh_f(cc[r]);
            hv[r] = h;
            unsigned short hi, lo; bsplit(h, hi, lo);
            hh[nb][4 * q + r][16 * w + c15] = hi;
            hl[nb][4 * q + r][16 * w + c15] = lo;
        }
        __syncthreads();
        pb = nb;
    }

#pragma unroll
    for (int r = 0; r < 4; r++) {
        const size_t si = (size_t)(BG + 4 * q + r) * H_ + 16 * w + c15;
        hS[si] = hv[r]; cS[si] = cc[r];
    }
}

// ---------------- X1 GEMM body (fragment-identical to old kXm) --------------
// 128 blocks; block g: fixed (m-tile, n-tile) = xy = g&31, dt = g>>5 step 4.
// 8 waves x 16 rows each. B tile staged once per block (XOR-swizzled).
__device__ __forceinline__ void runGemm(
    const unsigned short* __restrict__ Ah,  // [CL][1024][128]
    const unsigned short* __restrict__ Al,
    const unsigned short* __restrict__ Wh,  // [512][128]
    const unsigned short* __restrict__ Wl,
    const float* __restrict__ bias,         // [512]
    float* __restrict__ X1,                 // [CL][1024][512]
    int CL, int gbid,
    unsigned short* Bh, unsigned short* Bl)
{
    const int tid = threadIdx.x;
    const int xy  = gbid & 31;
    const int m0b = (xy >> 2) * 128;
    const int n0  = (xy & 3) * 128;

    for (int c = tid; c < 2048; c += 512) {
        const int n  = c >> 4;
        const int kb = (c & 15) << 4;
        const int sb = n * 256 + (kb ^ ((n & 7) << 4));
        *(float4*)((char*)Bh + sb) =
            *(const float4*)((const char*)Wh + (size_t)(n0 + n) * 256 + kb);
        *(float4*)((char*)Bl + sb) =
            *(const float4*)((const char*)Wl + (size_t)(n0 + n) * 256 + kb);
    }
    __syncthreads();

    const int lane = tid & 63;
    const int w    = tid >> 6;
    const int l15  = lane & 15;
    const int lq   = lane >> 4;
    const int m0   = m0b + w * 16;

    for (int dt = gbid >> 5; dt < CL; dt += 4) {
        const size_t arow = ((size_t)dt * B_ + m0 + l15) * H_;
        const unsigned short* a0h = Ah + arow;
        const unsigned short* a0l = Al + arow;

        floatx4 acc[8];
#pragma unroll
        for (int j = 0; j < 8; j++) acc[j] = (floatx4){0.f, 0.f, 0.f, 0.f};

#pragma unroll
        for (int ks = 0; ks < 4; ks++) {
            const int kk = ks * 32 + 8 * lq;
            const short8 ah = *(const short8*)(a0h + kk);
            const short8 al = *(const short8*)(a0l + kk);
            const int kbb = kk * 2;
#pragma unroll
            for (int nt = 0; nt < 8; nt++) {
                const int row = nt * 16 + l15;
                const int sb  = row * 256 + (kbb ^ ((row & 7) << 4));
                const short8 bh = *(const short8*)((const char*)Bh + sb);
                const short8 bl = *(const short8*)((const char*)Bl + sb);
                acc[nt] = __builtin_amdgcn_mfma_f32_16x16x32_bf16(ah, bh, acc[nt], 0, 0, 0);
                acc[nt] = __builtin_amdgcn_mfma_f32_16x16x32_bf16(ah, bl, acc[nt], 0, 0, 0);
                acc[nt] = __builtin_amdgcn_mfma_f32_16x16x32_bf16(al, bh, acc[nt], 0, 0, 0);
            }
        }

#pragma unroll
        for (int nt = 0; nt < 8; nt++) {
            const float bv = bias[n0 + nt * 16 + l15];
            const size_t orow = ((size_t)dt * B_ + m0 + lq * 4) * G_ + n0 + nt * 16 + l15;
#pragma unroll
            for (int r = 0; r < 4; r++)
                X1[orow + (size_t)r * G_] = acc[nt][r] + bv;
        }
    }
}

// -------- fused depth-3 pipeline: L0(c) | GEMM(c-1) | L1(c-2) ---------------
struct KFArgs {
    const float* feat;
    const unsigned short *H0h, *H0l;
    const float *wih0, *bias0;
    unsigned short *Ah0, *Al0, *Ah1, *Al1;
    float *h1S, *c1S;
    const unsigned short *Wh, *Wl;
    const float* bias1;
    float *X1a, *X1b;
    const unsigned short *H1h, *H1l;
    float *h2S, *c2S;
    int c, CL, NC;
};

__global__ __launch_bounds__(512, 2) void kF(KFArgs a) {
    __shared__ __align__(16) unsigned short hh[2][16][136];
    __shared__ __align__(16) unsigned short hl[2][16][136];
    __shared__ __align__(16) float fsh[672];
    __shared__ __align__(16) unsigned short Bh[128 * 128];
    __shared__ __align__(16) unsigned short Bl[128 * 128];

    const int c = a.c;
    if (blockIdx.x < 64) {
        if (c < a.NC) {
            unsigned short* Ah = (c & 1) ? a.Ah1 : a.Ah0;
            unsigned short* Al = (c & 1) ? a.Al1 : a.Al0;
            runL0(a.feat, a.H0h, a.H0l, a.wih0, a.bias0, Ah, Al, a.h1S, a.c1S,
                  c * a.CL, a.CL, blockIdx.x, hh, hl, fsh);
        }
    } else if (blockIdx.x < 192) {
        if (c >= 1 && c <= a.NC) {
            const int g = c - 1;
            const unsigned short* Ah = (g & 1) ? a.Ah1 : a.Ah0;
            const unsigned short* Al = (g & 1) ? a.Al1 : a.Al0;
            float* X1 = (g & 1) ? a.X1b : a.X1a;
            runGemm(Ah, Al, a.Wh, a.Wl, a.bias1, X1, a.CL, blockIdx.x - 64, Bh, Bl);
        }
    } else {
        if (c >= 2) {
            const int l = c - 2;
            const float* X1 = (l & 1) ? a.X1b : a.X1a;
            runL1(X1, a.H1h, a.H1l, a.h2S, a.c2S, l * a.CL, a.CL,
                  blockIdx.x - 192, hh, hl);
        }
    }
}

// ------------------------------------------- decoder (quad-gate both dots) --
__global__ __launch_bounds__(512, 2) void kD(
    const float* __restrict__ h1S, const float* __restrict__ c1S,
    const float* __restrict__ h2S, const float* __restrict__ c2S,
    const float* __restrict__ whh0P,  // [128][128][4] dec_Whh0 gate-packed (L2 stream)
    const float* __restrict__ wih0,   // [512]
    const float* __restrict__ b0,
    const float* __restrict__ packD1, // [128][128][8]
    const float* __restrict__ b1,
    const float* __restrict__ wo1,    // [128][128] W_out1 [hid][k] -> LDS rows
    const float* __restrict__ bo1,
    const float* __restrict__ wo2,
    const float* __restrict__ bo2,
    float* __restrict__ out)          // [B,TGT]
{
    __shared__ __align__(16) float h1_sh[H_ * 4];
    __shared__ __align__(16) float h2_sh[H_ * 4];
    __shared__ __align__(16) float h2t[4][H_];       // [bb][hid]
    __shared__ __align__(16) float zp[4 * 2048];
    __shared__ __align__(16) float wo1s[H_ * 132];   // rows [hid][k], pad 132
    __shared__ float rp[8];

    const int tid = threadIdx.x;
    const int hid = tid & 127;        // gate group / act hid
    const int bb  = tid >> 7;         // k-quarter / act batch
    const int B0  = blockIdx.x * 4;

    const float b0i = b0[hid],        b0f = b0[hid + 128];
    const float b0g = b0[hid + 256],  b0o = b0[hid + 384];
    const float wxi = wih0[hid],      wxf = wih0[hid + 128];
    const float wxg = wih0[hid + 256], wxo = wih0[hid + 384];
    const float b1i = b1[hid],        b1f = b1[hid + 128];
    const float b1g = b1[hid + 256],  b1o = b1[hid + 384];

    for (int t = tid; t < H_ * 32; t += 512) {
        const int r = t >> 5, q = t & 31;
        *(float4*)&wo1s[r * 132 + q * 4] = *(const float4*)&wo1[r * H_ + q * 4];
    }

    const float wo2v = wo2[hid];
    const float bo1j = bo1[hid];
    const float bo2v = bo2[0];

    float c1 = c1S[(B0 + bb) * H_ + hid];
    float c2 = c2S[(B0 + bb) * H_ + hid];
    h1_sh[hid * 4 + bb] = h1S[(B0 + bb) * H_ + hid];
    {
        const float h2v = h2S[(B0 + bb) * H_ + hid];
        h2_sh[hid * 4 + bb] = h2v;
        h2t[bb][hid] = h2v;
    }
    if (tid < 8) rp[tid] = -0.5f * bo2v;   // so pred(step 0) = 0
    __syncthreads();

    const float* hb1 = h1_sh + bb * 128;
    const float* hb2 = h2_sh + bb * 128;
    const float* pk  = packD1 + ((size_t)bb * 32 * H_ + hid) * 8;
    const float* pw0 = whh0P + (size_t)bb * 32 * 512 + hid * 4;   // [k][hid][4] slice

    for (int s = 0; s < TGT_; s++) {
        // ===== phase 1: L0 h-dot (L2 weight stream) + head of h2(s-1) =====
        {
            float a[4][4] = {};
#pragma unroll 8
            for (int k = 0; k < 32; k++) {
                const float4 wv = *(const float4*)&pw0[(size_t)k * 512];  // gates i,f,g,o
                const float4 h4 = *(const float4*)&hb1[k * 4];
                a[0][0] = __fmaf_rn(h4.x, wv.x, a[0][0]);
                a[0][1] = __fmaf_rn(h4.y, wv.x, a[0][1]);
                a[0][2] = __fmaf_rn(h4.z, wv.x, a[0][2]);
                a[0][3] = __fmaf_rn(h4.w, wv.x, a[0][3]);
                a[1][0] = __fmaf_rn(h4.x, wv.y, a[1][0]);
                a[1][1] = __fmaf_rn(h4.y, wv.y, a[1][1]);
                a[1][2] = __fmaf_rn(h4.z, wv.y, a[1][2]);
                a[1][3] = __fmaf_rn(h4.w, wv.y, a[1][3]);
                a[2][0] = __fmaf_rn(h4.x, wv.z, a[2][0]);
                a[2][1] = __fmaf_rn(h4.y, wv.z, a[2][1]);
                a[2][2] = __fmaf_rn(h4.z, wv.z, a[2][2]);
                a[2][3] = __fmaf_rn(h4.w, wv.z, a[2][3]);
                a[3][0] = __fmaf_rn(h4.x, wv.w, a[3][0]);
                a[3][1] = __fmaf_rn(h4.y, wv.w, a[3][1]);
                a[3][2] = __fmaf_rn(h4.z, wv.w, a[3][2]);
                a[3][3] = __fmaf_rn(h4.w, wv.w, a[3][3]);
            }
#pragma unroll
            for (int g = 0; g < 4; g++)
#pragma unroll
                for (int b = 0; b < 4; b++)
                    zp[bb * 2048 + b * 512 + hid + 128 * g] = a[g][b];
        }
        {
            float hacc = bo1j;
#pragma unroll
            for (int q = 0; q < 32; q++) {
                const float4 hq = *(const float4*)&h2t[bb][q * 4];          // uniform
                const float4 wq = *(const float4*)&wo1s[hid * 132 + q * 4]; // lane-spread
                hacc = __fmaf_rn(hq.x, wq.x, hacc);
                hacc = __fmaf_rn(hq.y, wq.y, hacc);
                hacc = __fmaf_rn(hq.z, wq.z, hacc);
                hacc = __fmaf_rn(hq.w, wq.w, hacc);
            }
            float p = fmaxf(hacc, 0.f) * wo2v;
            p += __shfl_down(p, 32); p += __shfl_down(p, 16); p += __shfl_down(p, 8);
            p += __shfl_down(p, 4);  p += __shfl_down(p, 2);  p += __shfl_down(p, 1);
            if ((tid & 63) == 0) rp[tid >> 6] = p;
        }
        __syncthreads();

        // ===== phase 2: L0 act (+ x-term via pred), out write =====
        {
            const float pred = rp[2 * bb] + rp[2 * bb + 1] + bo2v;
            if (hid == 0 && s > 0) out[(B0 + bb) * TGT_ + (s - 1)] = pred;
            const int base = bb * 512 + hid;
            float zi = __fmaf_rn(wxi, pred, b0i);
            float zf = __fmaf_rn(wxf, pred, b0f);
            float zg = __fmaf_rn(wxg, pred, b0g);
            float zo = __fmaf_rn(wxo, pred, b0o);
#pragma unroll
            for (int q = 0; q < 4; q++) {
                zi += zp[q * 2048 + base];
                zf += zp[q * 2048 + base + 128];
                zg += zp[q * 2048 + base + 256];
                zo += zp[q * 2048 + base + 384];
            }
            c1 = sigm(zf) * c1 + sigm(zi) * tanh_f(zg);
            h1_sh[hid * 4 + bb] = sigm(zo) * tanh_f(c1);
        }
        __syncthreads();

        // ===== phase 3: L1 dot (L2 stream: 32 contiguous B per thread per k) =====
        {
            float d[4][4] = {};
#pragma unroll 8
            for (int k = 0; k < 32; k++) {
                const float4 wi = *(const float4*)&pk[(size_t)k * 1024];
                const float4 wh = *(const float4*)&pk[(size_t)k * 1024 + 4];
                const float4 p1 = *(const float4*)&hb1[k * 4];
                const float4 p2 = *(const float4*)&hb2[k * 4];
                d[0][0] = __fmaf_rn(p1.x, wi.x, __fmaf_rn(p2.x, wh.x, d[0][0]));
                d[0][1] = __fmaf_rn(p1.y, wi.x, __fmaf_rn(p2.y, wh.x, d[0][1]));
                d[0][2] = __fmaf_rn(p1.z, wi.x, __fmaf_rn(p2.z, wh.x, d[0][2]));
                d[0][3] = __fmaf_rn(p1.w, wi.x, __fmaf_rn(p2.w, wh.x, d[0][3]));
                d[1][0] = __fmaf_rn(p1.x, wi.y, __fmaf_rn(p2.x, wh.y, d[1][0]));
                d[1][1] = __fmaf_rn(p1.y, wi.y, __fmaf_rn(p2.y, wh.y, d[1][1]));
                d[1][2] = __fmaf_rn(p1.z, wi.y, __fmaf_rn(p2.z, wh.y, d[1][2]));
                d[1][3] = __fmaf_rn(p1.w, wi.y, __fmaf_rn(p2.w, wh.y, d[1][3]));
                d[2][0] = __fmaf_rn(p1.x, wi.z, __fmaf_rn(p2.x, wh.z, d[2][0]));
                d[2][1] = __fmaf_rn(p1.y, wi.z, __fmaf_rn(p2.y, wh.z, d[2][1]));
                d[2][2] = __fmaf_rn(p1.z, wi.z, __fmaf_rn(p2.z, wh.z, d[2][2]));
                d[2][3] = __fmaf_rn(p1.w, wi.z, __fmaf_rn(p2.w, wh.z, d[2][3]));
                d[3][0] = __fmaf_rn(p1.x, wi.w, __fmaf_rn(p2.x, wh.w, d[3][0]));
                d[3][1] = __fmaf_rn(p1.y, wi.w, __fmaf_rn(p2.y, wh.w, d[3][1]));
                d[3][2] = __fmaf_rn(p1.z, wi.w, __fmaf_rn(p2.z, wh.w, d[3][2]));
                d[3][3] = __fmaf_rn(p1.w, wi.w, __fmaf_rn(p2.w, wh.w, d[3][3]));
            }
#pragma unroll
            for (int g = 0; g < 4; g++)
#pragma unroll
                for (int b = 0; b < 4; b++)
                    zp[bb * 2048 + b * 512 + hid + 128 * g] = d[g][b];
        }
        __syncthreads();

        // ===== phase 4: L1 act =====
        {
            const int base = bb * 512 + hid;
            float zi = b1i, zf = b1f, zg = b1g, zo = b1o;
#pragma unroll
            for (int q = 0; q < 4; q++) {
                zi += zp[q * 2048 + base];
                zf += zp[q * 2048 + base + 128];
                zg += zp[q * 2048 + base + 256];
                zo += zp[q * 2048 + base + 384];
            }
            c2 = sigm(zf) * c2 + sigm(zi) * tanh_f(zg);
            const float h2v = sigm(zo) * tanh_f(c2);
            h2_sh[hid * 4 + bb] = h2v;
            h2t[bb][hid] = h2v;
        }
        __syncthreads();
    }

    // ===== epilogue: head of final h2 -> out[..][95] =====
    {
        float hacc = bo1j;
#pragma unroll
        for (int q = 0; q < 32; q++) {
            const float4 hq = *(const float4*)&h2t[bb][q * 4];
            const float4 wq = *(const float4*)&wo1s[hid * 132 + q * 4];
            hacc = __fmaf_rn(hq.x, wq.x, hacc);
            hacc = __fmaf_rn(hq.y, wq.y, hacc);
            hacc = __fmaf_rn(hq.z, wq.z, hacc);
            hacc = __fmaf_rn(hq.w, wq.w, hacc);
        }
        float p = fmaxf(hacc, 0.f) * wo2v;
        p += __shfl_down(p, 32); p += __shfl_down(p, 16); p += __shfl_down(p, 8);
        p += __shfl_down(p, 4);  p += __shfl_down(p, 2);  p += __shfl_down(p, 1);
        if ((tid & 63) == 0) rp[tid >> 6] = p;
    }
    __syncthreads();
    if (tid < 4)
        out[(B0 + tid) * TGT_ + (TGT_ - 1)] = rp[2 * tid] + rp[2 * tid + 1] + bo2v;
}

// ---------------------------------------------------------------- launch ----
extern "C" void kernel_launch(void* const* d_in, const int* in_sizes, int n_in,
                              void* d_out, int out_size, void* d_ws, size_t ws_size,
                              hipStream_t stream) {
    const float* feat  = (const float*)d_in[0];
    const float* eWih0 = (const float*)d_in[1];
    const float* eWhh0 = (const float*)d_in[2];
    const float* eB0   = (const float*)d_in[3];
    const float* eWih1 = (const float*)d_in[4];
    const float* eWhh1 = (const float*)d_in[5];
    const float* eB1   = (const float*)d_in[6];
    const float* dWih0 = (const float*)d_in[7];
    const float* dWhh0 = (const float*)d_in[8];
    const float* dB0   = (const float*)d_in[9];
    const float* dWih1 = (const float*)d_in[10];
    const float* dWhh1 = (const float*)d_in[11];
    const float* dB1   = (const float*)d_in[12];
    const float* Wo1   = (const float*)d_in[13];
    const float* bo1   = (const float*)d_in[14];
    const float* Wo2   = (const float*)d_in[15];
    const float* bo2   = (const float*)d_in[16];

    const size_t SZ_BH = (size_t)B_ * H_;     // 131072
    const size_t SZ_W  = (size_t)G_ * H_;     // 65536
    const size_t fixed_f = 4 * SZ_BH + 6 * SZ_W + 64;

    // Double-buffered A (2*CL*B*H floats-equiv) + X1 (2*CL*B*G floats).
    static const int cands[] = {42, 32, 28, 24, 21, 16, 14, 12, 8, 7, 6, 4, 3, 2, 1};
    int CL = 1;
    for (int ci = 0; ci < 15; ci++) {
        const size_t need = (fixed_f + 2 * (size_t)cands[ci] * B_ * (H_ + G_)) * 4;
        if (need <= ws_size) { CL = cands[ci]; break; }
    }
    const int NC = T_ / CL;

    float* ws = (float*)d_ws;
    unsigned short* Ah0 = (unsigned short*)ws;           // [CL][1024][128] bf16-hi, buf 0
    unsigned short* Al0 = Ah0 + (size_t)CL * B_ * H_;
    unsigned short* Ah1 = Al0 + (size_t)CL * B_ * H_;    // buf 1
    unsigned short* Al1 = Ah1 + (size_t)CL * B_ * H_;
    float* X1a   = ws + 2 * (size_t)CL * B_ * H_;        // [CL][1024][512], buf 0
    float* X1b   = X1a + (size_t)CL * B_ * G_;           // buf 1
    float* h1S   = X1b + (size_t)CL * B_ * G_;
    float* c1S   = h1S + SZ_BH;
    float* h2S   = c1S + SZ_BH;
    float* c2S   = h2S + SZ_BH;
    float* pk0   = c2S + SZ_BH;                          // [128][128][4] (SZ_W floats)
    float* wtD1p = pk0 + SZ_W;                           // [128][128][8] = 2*SZ_W
    unsigned short* Wh  = (unsigned short*)(wtD1p + 2 * SZ_W);  // eWih1 split
    unsigned short* Wl  = Wh + SZ_W;
    unsigned short* H0h = Wl + SZ_W;                            // eWhh0 split
    unsigned short* H0l = H0h + SZ_W;
    unsigned short* H1h = H0l + SZ_W;                           // eWhh1 split
    unsigned short* H1l = H1h + SZ_W;

    PrepArgs pa;
    pa.dwhh0 = dWhh0; pa.pk0 = pk0;
    pa.d1x = dWih1; pa.d1h = dWhh1; pa.pack = wtD1p;
    pa.bsrc[0] = eWih1; pa.bh[0] = Wh;  pa.bl[0] = Wl;
    pa.bsrc[1] = eWhh0; pa.bh[1] = H0h; pa.bl[1] = H0l;
    pa.bsrc[2] = eWhh1; pa.bh[2] = H1h; pa.bl[2] = H1l;
    kPrep<<<5, 256, 0, stream>>>(pa);

    KFArgs fa;
    fa.feat = feat; fa.H0h = H0h; fa.H0l = H0l; fa.wih0 = eWih0; fa.bias0 = eB0;
    fa.Ah0 = Ah0; fa.Al0 = Al0; fa.Ah1 = Ah1; fa.Al1 = Al1;
    fa.h1S = h1S; fa.c1S = c1S;
    fa.Wh = Wh; fa.Wl = Wl; fa.bias1 = eB1;
    fa.X1a = X1a; fa.X1b = X1b;
    fa.H1h = H1h; fa.H1l = H1l; fa.h2S = h2S; fa.c2S = c2S;
    fa.CL = CL; fa.NC = NC;

    // Depth-3 pipeline: per launch c — L0(c) | GEMM(c-1) | L1(c-2).
    // All deps are stream-order between launches; races removed by parity
    // double-buffering of A and X1.
    for (int c = 0; c <= NC + 1; c++) {
        fa.c = c;
        kF<<<256, 512, 0, stream>>>(fa);
    }
    kD<<<NBLK_, 512, 0, stream>>>(h1S, c1S, h2S, c2S,
                                  pk0, dWih0, dB0,
                                  wtD1p, dB1,
                                  Wo1, bo1, Wo2, bo2,
                                  (float*)d_out);
}